// Round 8
// baseline (154.347 us; speedup 1.0000x reference)
//
#include <hip/hip_runtime.h>

typedef unsigned short u16;
typedef __attribute__((ext_vector_type(8))) short bh8;
typedef __attribute__((ext_vector_type(4))) short s4;
typedef __attribute__((ext_vector_type(4))) short bh4;
typedef __attribute__((ext_vector_type(4))) float fx4;

__device__ __forceinline__ u16 f2b(float f) {
  union { float f; unsigned u; } v; v.f = f;
  unsigned r = v.u + 0x7fffu + ((v.u >> 16) & 1u);
  return (u16)(r >> 16);
}
__device__ __forceinline__ float b2f(u16 h) {
  union { unsigned u; float f; } v; v.u = ((unsigned)h) << 16; return v.f;
}

// fast 2^x
__device__ __forceinline__ float ex2(float x) {
#if __has_builtin(__builtin_amdgcn_exp2f)
  return __builtin_amdgcn_exp2f(x);
#else
  return __expf(x * 0.6931471805599453f);
#endif
}

// packed f32x2 -> bf16x2 (RNE, matches f2b)
__device__ __forceinline__ unsigned cvtpk(float lo, float hi) {
  unsigned r;
  asm("v_cvt_pk_bf16_f32 %0, %1, %2" : "=v"(r) : "v"(lo), "v"(hi));
  return r;
}

// 16x16x16 bf16 MFMA (K=16)
#if __has_builtin(__builtin_amdgcn_mfma_f32_16x16x16bf16_1k)
__device__ __forceinline__ fx4 pv_mfma(s4 a, s4 b, fx4 c) {
  return __builtin_amdgcn_mfma_f32_16x16x16bf16_1k(a, b, c, 0, 0, 0);
}
#else
__device__ __forceinline__ fx4 pv_mfma(s4 a, s4 b, fx4 c) {
  asm("v_mfma_f32_16x16x16_bf16 %0, %1, %2, %0" : "+v"(c) : "v"(a), "v"(b));
  return c;
}
#endif

// ---------- prep: weights -> bf16, transposed to [N][K]; Wq scaled by dh^-0.5 * log2(e) ----------
__global__ __launch_bounds__(256) void conv_w_k(const float* __restrict__ Wq, const float* __restrict__ Wk,
                         const float* __restrict__ Wv, const float* __restrict__ Wo,
                         const float* __restrict__ W1, const float* __restrict__ W2,
                         u16* __restrict__ WqkvT, u16* __restrict__ WoT,
                         u16* __restrict__ W1T, u16* __restrict__ W2T) {
  int i = blockIdx.x * 256 + threadIdx.x;
  if (i < 196608) {                       // WqkvT [768][256]
    int n = i >> 8, k = i & 255; float v;
    if (n < 256) v = Wq[k*256+n] * 0.25503487359f;   // 1/sqrt(32) * log2(e)
    else if (n < 512) v = Wk[k*256+(n-256)];
    else v = Wv[k*256+(n-512)];
    WqkvT[i] = f2b(v);
  } else if (i < 262144) {                // WoT [256][256]
    int j = i - 196608; int n = j >> 8, k = j & 255;
    WoT[j] = f2b(Wo[k*256+n]);
  } else if (i < 393216) {                // W1T [512][256]
    int j = i - 262144; int n = j >> 8, k = j & 255;
    W1T[j] = f2b(W1[k*512+n]);
  } else {                                // W2T [256][512]
    int j = i - 393216; int n = j >> 9, k = j & 511;
    W2T[j] = f2b(W2[k*256+n]);
  }
}

// ---------- QKV GEMM: persistent-B, barrier-free K-loop ----------
// R7: every barrier'd-staging variant sits at 42-54us (= m97-structure curve).
// Escape hatch specific to K=256: B slice [64 n][256 k] bf16 = 32KB lives in
// LDS for the whole kernel (loaded once, source XOR-pre-swizzled, rule #21).
// 4 waves each compute an independent 64x64 tile: A fragments read DIRECTLY
// from global f32 (16 rows x 64B fully-consumed lines) -> cvt_pk -> MFMA;
// B via swizzled ds_read_b128 (2-way conflict = free). ZERO barriers and zero
// vmcnt drains in the K-loop -> compiler pipelines loads across the whole
// unrolled K range; latency hiding via ILP, not lockstep TLP.
// Epilogue: one __syncthreads (B dead), C tile aliases B region, swizzled
// LDS round-trip -> coalesced 16B stores (proven R0 pattern).
__global__ __launch_bounds__(256) void qkv_k(
    const float* __restrict__ X, const u16* __restrict__ BT,
    u16* __restrict__ qw, u16* __restrict__ kw, u16* __restrict__ vtw) {
  __shared__ u16 smem[16384];            // B [64][256] bf16 = 32KB; reused as C tile
  constexpr int nx = 12;                 // 12 n-slices of 64 (q:0-3, k:4-7, v:8-11)
  const int lid = blockIdx.y * nx + blockIdx.x;
  const int xcd = lid & 7;
  const int jj2 = lid >> 3;
  const int m0 = (xcd * (gridDim.y >> 3) + jj2 / nx) * 256;
  const int n0 = (jj2 % nx) * 64;
  const int tid = threadIdx.x, lane = tid & 63, wv = tid >> 6;
  const int lg = lane >> 4, ll = lane & 15;

  // ---- one-time B load: 64 rows x 32 chunks(16B), source pre-swizzled ----
  // LDS[row][kc] holds BT[n0+row][(kc^(row&7))*8 .. +8]
#pragma unroll
  for (int i = 0; i < 8; ++i) {
    int c = i*256 + tid;
    int row = c >> 5, kc = c & 31;
    const u16* gp = BT + (size_t)(n0+row)*256 + ((kc ^ (row & 7)) << 3);
    int lbase = (i*256 + wv*64) * 8;
    __builtin_amdgcn_global_load_lds((const __attribute__((address_space(1))) void*)gp,
        (__attribute__((address_space(3))) void*)&smem[lbase], 16, 0, 0);
  }
  __syncthreads();                       // drains vmcnt; B visible to all waves

  fx4 acc[4][4] = {};
  const float* aw = X + (size_t)(m0 + wv*64)*256;

#pragma unroll
  for (int t = 0; t < 8; ++t) {
    bh8 af[4], bfr[4];
#pragma unroll
    for (int mi = 0; mi < 4; ++mi) {
      const float* ap = aw + (size_t)(mi*16 + ll)*256 + t*32 + lg*8;
      float4 a0 = *(const float4*)ap;
      float4 a1 = *(const float4*)(ap + 4);
      union { unsigned u[4]; bh8 v; } cvt;
      cvt.u[0] = cvtpk(a0.x, a0.y); cvt.u[1] = cvtpk(a0.z, a0.w);
      cvt.u[2] = cvtpk(a1.x, a1.y); cvt.u[3] = cvtpk(a1.z, a1.w);
      af[mi] = cvt.v;
    }
#pragma unroll
    for (int ni = 0; ni < 4; ++ni) {
      int row = ni*16 + ll;
      bfr[ni] = *(const bh8*)&smem[row*256 + (((t*4 + lg) ^ (ll & 7)) << 3)];
    }
#pragma unroll
    for (int mi = 0; mi < 4; ++mi)
#pragma unroll
      for (int ni = 0; ni < 4; ++ni)
        acc[mi][ni] = __builtin_amdgcn_mfma_f32_16x16x32_bf16(af[mi], bfr[ni], acc[mi][ni], 0, 0, 0);
  }

  // ---- epilogue ----
  __syncthreads();                       // all waves done reading B
  const bool vt = (n0 >= 512);

  if (!vt) {
    // C tile [256 m][64 n] u16 = 32KB; col swizzle: n ^ ((m&7)<<3)
#pragma unroll
    for (int mi = 0; mi < 4; ++mi)
#pragma unroll
      for (int ni = 0; ni < 4; ++ni) {
        fx4 v = acc[mi][ni];
        int n = ni*16 + ll;
#pragma unroll
        for (int ii = 0; ii < 2; ++ii) {
          unsigned pk = cvtpk(v[2*ii], v[2*ii+1]);
          int mA = wv*64 + mi*16 + lg*4 + 2*ii;
          int mB = mA + 1;
          smem[mA*64 + (n ^ ((mA & 7) << 3))] = (u16)pk;
          smem[mB*64 + (n ^ ((mB & 7) << 3))] = (u16)(pk >> 16);
        }
      }
  } else {
    // transposed C tile [64 n][256 m] u16; m swizzle: mb ^ ((n&7)<<3) (8B granules stay aligned)
#pragma unroll
    for (int mi = 0; mi < 4; ++mi)
#pragma unroll
      for (int ni = 0; ni < 4; ++ni) {
        fx4 v = acc[mi][ni];
        int n = ni*16 + ll;
        int mb = wv*64 + mi*16 + lg*4;
        uint2 pk;
        pk.x = cvtpk(v[0], v[1]);
        pk.y = cvtpk(v[2], v[3]);
        *(uint2*)&smem[n*256 + (mb ^ ((n & 7) << 3))] = pk;
      }
  }
  __syncthreads();

#pragma unroll
  for (int j = 0; j < 8; ++j) {
    int cid = tid + 256*j;
    if (!vt) {                           // q/k: [b][h][l][32], 8 contiguous d
      int row = cid >> 3, g = cid & 7;   // row = m-idx 0..255, g = n-granule
      bh8 val = *(const bh8*)&smem[row*64 + ((g*8) ^ ((row & 7) << 3))];
      int m = m0 + row; int b = m >> 10, l = m & 1023;
      int n = n0 + g*8; int hh = (n >> 5) & 7, d = n & 31;
      size_t bh_ = (size_t)(b*8 + hh);
      u16* dst = (n0 < 256) ? qw : kw;
      *(bh8*)&dst[(bh_*1024 + l)*32 + d] = val;
    } else {                             // vT: [b][h][32][1024], 8 contiguous l
      int row = cid >> 5, mc = cid & 31; // row = n-idx 0..63, mc = m-granule
      bh8 val = *(const bh8*)&smem[row*256 + ((mc*8) ^ ((row & 7) << 3))];
      int n = n0 + row; int hh = (n >> 5) & 7, d = n & 31;
      int m = m0 + mc*8; int b = m >> 10, l = m & 1023;
      size_t bh_ = (size_t)(b*8 + hh);
      *(bh8*)&vtw[(bh_*32 + d)*1024 + l] = val;
    }
  }
}

// ---------- GEMM: C[M][N] = A[M][K] * BT[N][K]^T, bf16 in, fp32 acc ----------
// Verbatim R3 (proven): 128x128 tile, 2-phase __syncthreads K-loop.
// Only instantiated with AF32=0 now (W1 gemm).
template<int K, int N, int EPI, int AF32>
__global__ __launch_bounds__(256) void gemm_k(
    const void* __restrict__ Av, const u16* __restrict__ BT,
    u16* __restrict__ C0, u16* __restrict__ C1, u16* __restrict__ C2,
    const float* __restrict__ bias) {
  constexpr int BK = 32;
  constexpr int ABUF = AF32 ? 8192 : 4096;
  constexpr int BOFF = AF32 ? 16384 : 8192;
  __shared__ u16 smem[AF32 ? 24576 : 16384];
  const int nx = gridDim.x;
  const int lid = blockIdx.y * nx + blockIdx.x;
  const int xcd = lid & 7;
  const int jj2 = lid >> 3;
  const int m0 = (xcd * (gridDim.y >> 3) + jj2 / nx) * 128;
  const int n0 = (jj2 % nx) * 128;
  const int tid = threadIdx.x, lane = tid & 63, wv = tid >> 6;
  const int wr = wv >> 1, wc = wv & 1, lg = lane >> 4, ll = lane & 15;
  const u16* A16 = (const u16*)Av;
  const float* A32 = (const float*)Av;

  fx4 acc[4][4] = {};

  auto stageB = [&](int buf, int ks) {
#pragma unroll
    for (int i = 0; i < 2; ++i) {
      int c = i*256 + tid;
      int row = c >> 2, ko = (c & 3) * 8;
      const u16* gpB = BT + (size_t)(n0+row)*K + ks + ko;
      int lbase = BOFF + buf*4096 + (i*256 + wv*64) * 8;
      __builtin_amdgcn_global_load_lds((const __attribute__((address_space(1))) void*)gpB,
          (__attribute__((address_space(3))) void*)&smem[lbase], 16, 0, 0);
    }
  };
  auto stageA16 = [&](int buf, int ks) {
#pragma unroll
    for (int i = 0; i < 2; ++i) {
      int c = i*256 + tid;
      int row = c >> 2, ko = (c & 3) * 8;
      const u16* gpA = A16 + (size_t)(m0+row)*K + ks + ko;
      int lbase = buf*ABUF + (i*256 + wv*64) * 8;
      __builtin_amdgcn_global_load_lds((const __attribute__((address_space(1))) void*)gpA,
          (__attribute__((address_space(3))) void*)&smem[lbase], 16, 0, 0);
    }
  };
  auto stageA32 = [&](int buf, int ks) {
#pragma unroll
    for (int i = 0; i < 4; ++i) {
      int c = i*256 + tid;
      int r = c >> 3;
      int po = (c & 7) * 16;
      int lo = po ^ ((r & 7) << 4);
      const float* gpA = A32 + (size_t)(m0 + r)*K + ks + (lo >> 2);
      int lbase = buf*ABUF + (i*256 + wv*64) * 8;
      __builtin_amdgcn_global_load_lds((const __attribute__((address_space(1))) void*)gpA,
          (__attribute__((address_space(3))) void*)&smem[lbase], 16, 0, 0);
    }
  };

  constexpr int NT = K / BK;
  if constexpr (AF32) stageA32(0, 0); else stageA16(0, 0);
  stageB(0, 0);
  __syncthreads();
  int cur = 0;
  for (int t = 0; t < NT; ++t) {
    if (t + 1 < NT) {
      if constexpr (AF32) stageA32(cur ^ 1, (t+1)*BK); else stageA16(cur ^ 1, (t+1)*BK);
      stageB(cur ^ 1, (t+1)*BK);
    }
    bh8 af[4], bfr[4];
    if constexpr (AF32) {
#pragma unroll
      for (int mi = 0; mi < 4; ++mi) {
        int r = wr*64 + mi*16 + ll;
        int sw = (r & 7) << 4;
        int b0 = r*128 + ((lg*32) ^ sw);
        int b1 = r*128 + ((lg*32 + 16) ^ sw);
        float4 a0 = *(const float4*)&smem[cur*ABUF + (b0 >> 1)];
        float4 a1 = *(const float4*)&smem[cur*ABUF + (b1 >> 1)];
        union { unsigned u[4]; bh8 v; } cvt;
        cvt.u[0] = cvtpk(a0.x, a0.y); cvt.u[1] = cvtpk(a0.z, a0.w);
        cvt.u[2] = cvtpk(a1.x, a1.y); cvt.u[3] = cvtpk(a1.z, a1.w);
        af[mi] = cvt.v;
      }
    } else {
#pragma unroll
      for (int mi = 0; mi < 4; ++mi)
        af[mi] = *(const bh8*)&smem[cur*ABUF + (wr*64 + mi*16 + ll)*BK + lg*8];
    }
#pragma unroll
    for (int ni = 0; ni < 4; ++ni)
      bfr[ni] = *(const bh8*)&smem[BOFF + cur*4096 + (wc*64 + ni*16 + ll)*BK + lg*8];
#pragma unroll
    for (int mi = 0; mi < 4; ++mi)
#pragma unroll
      for (int ni = 0; ni < 4; ++ni)
        acc[mi][ni] = __builtin_amdgcn_mfma_f32_16x16x32_bf16(af[mi], bfr[ni], acc[mi][ni], 0, 0, 0);
    __syncthreads();
    cur ^= 1;
  }

  // ---- epilogue: acc -> LDS (swizzled) -> coalesced 16B stores ----
  auto swz = [](int r) { return ((r & 14) << 2) ^ ((r & 3) << 5); };

  {
    float bv[4];
    if constexpr (EPI >= 2) {
#pragma unroll
      for (int ni = 0; ni < 4; ++ni) bv[ni] = bias[n0 + wc*64 + ni*16 + ll];
    }
#pragma unroll
    for (int mi = 0; mi < 4; ++mi)
#pragma unroll
      for (int ni = 0; ni < 4; ++ni) {
        fx4 v = acc[mi][ni];
        int n = wc*64 + ni*16 + ll;
#pragma unroll
        for (int ii = 0; ii < 2; ++ii) {
          float x0 = v[2*ii], x1 = v[2*ii+1];
          if constexpr (EPI == 2) { x0 = fmaxf(x0 + bv[ni], 0.f); x1 = fmaxf(x1 + bv[ni], 0.f); }
          unsigned pk = cvtpk(x0, x1);
          int mA = wr*64 + mi*16 + lg*4 + 2*ii;
          int mB = mA + 1;
          smem[mA*128 + (n ^ swz(mA))] = (u16)pk;
          smem[mB*128 + (n ^ swz(mB))] = (u16)(pk >> 16);
        }
      }
  }
  __syncthreads();

#pragma unroll
  for (int j = 0; j < 8; ++j) {
    int cid = tid + 256*j;
    int row = cid >> 4, c8 = (cid & 15) << 3;
    bh8 val = *(const bh8*)&smem[row*128 + (c8 ^ swz(row))];
    *(bh8*)&C0[(size_t)(m0+row)*N + n0 + c8] = val;
  }
}

// ---------- fused GEMM + residual + LayerNorm ----------
// Verbatim R3 passing version: 64x256 tile, 4 waves, 2-buf __syncthreads.
template<int K, int RF32, int OF32, int BIAS>
__global__ __launch_bounds__(256) void gemm_ln_k(
    const u16* __restrict__ A, const u16* __restrict__ BT,
    const void* __restrict__ resid, const float* __restrict__ bias,
    const float* __restrict__ g, const float* __restrict__ b,
    void* __restrict__ out) {
  constexpr int BK = 32;
  __shared__ u16 smem[20480];   // A dbuf [2][2048) @0, B dbuf [2][8192) @4096; C tile [64][256] @0
  const int lid = blockIdx.y;
  const int xcd = lid & 7;
  const int jj2 = lid >> 3;
  const int m0 = (xcd * (gridDim.y >> 3) + jj2) * 64;
  const int tid = threadIdx.x, lane = tid & 63, wv = tid >> 6;
  const int wr = wv >> 1, wc = wv & 1, lg = lane >> 4, ll = lane & 15;

  fx4 acc[2][8] = {};

  auto stage = [&](int buf, int ks) {
    {
      int c = tid;
      int row = c >> 2, ko = (c & 3) * 8;
      const u16* gpA = A + (size_t)(m0+row)*K + ks + ko;
      int lbase = wv*512;
      __builtin_amdgcn_global_load_lds((const __attribute__((address_space(1))) void*)gpA,
          (__attribute__((address_space(3))) void*)&smem[buf*2048 + lbase], 16, 0, 0);
    }
#pragma unroll
    for (int i = 0; i < 4; ++i) {
      int c = i*256 + tid;
      int row = c >> 2, ko = (c & 3) * 8;
      const u16* gpB = BT + (size_t)row*K + ks + ko;
      int lbase = (i*256 + wv*64) * 8;
      __builtin_amdgcn_global_load_lds((const __attribute__((address_space(1))) void*)gpB,
          (__attribute__((address_space(3))) void*)&smem[4096 + buf*8192 + lbase], 16, 0, 0);
    }
  };

  constexpr int NT = K / BK;
  stage(0, 0);
  __syncthreads();
  int cur = 0;
  for (int t = 0; t < NT; ++t) {
    if (t + 1 < NT) stage(cur ^ 1, (t+1)*BK);
    bh8 af[2], bfr[8];
#pragma unroll
    for (int mi = 0; mi < 2; ++mi)
      af[mi] = *(const bh8*)&smem[cur*2048 + (wr*32 + mi*16 + ll)*BK + lg*8];
#pragma unroll
    for (int ni = 0; ni < 8; ++ni)
      bfr[ni] = *(const bh8*)&smem[4096 + cur*8192 + (wc*128 + ni*16 + ll)*BK + lg*8];
#pragma unroll
    for (int mi = 0; mi < 2; ++mi)
#pragma unroll
      for (int ni = 0; ni < 8; ++ni)
        acc[mi][ni] = __builtin_amdgcn_mfma_f32_16x16x32_bf16(bfr[ni], af[mi], acc[mi][ni], 0, 0, 0);
    __syncthreads();
    cur ^= 1;
  }

  // stage C tile: row m_l = wr*32+mi*16+ll, cols n_l..n_l+3 = wc*128+ni*16+lg*4
#pragma unroll
  for (int mi = 0; mi < 2; ++mi) {
    int m_l = wr*32 + mi*16 + ll;
    int sx = (m_l & 7) << 1;
#pragma unroll
    for (int ni = 0; ni < 8; ++ni) {
      fx4 v = acc[mi][ni];
      int gidx = (wc*32 + ni*4 + lg) ^ sx;
      uint2 pk;
      pk.x = cvtpk(v[0], v[1]);
      pk.y = cvtpk(v[2], v[3]);
      *(uint2*)&smem[m_l*256 + gidx*4] = pk;
    }
  }
  __syncthreads();

  // per-row LN: wave wv handles rows wv*16 .. wv*16+15; lane covers cols lane*4..+3
  const int c0 = lane * 4;
  float4 gv = *(const float4*)&g[c0];
  float4 bv = *(const float4*)&b[c0];
  float4 biasv = {0.f, 0.f, 0.f, 0.f};
  if constexpr (BIAS) biasv = *(const float4*)&bias[c0];
#pragma unroll 4
  for (int rr = 0; rr < 16; ++rr) {
    int r = wv*16 + rr;
    bh4 yv = *(const bh4*)&smem[r*256 + ((lane ^ ((r & 7) << 1)) << 2)];
    size_t gbase = (size_t)(m0 + r) * 256 + c0;
    float s0, s1, s2, s3;
    if constexpr (RF32) {
      float4 xv = *(const float4*)&((const float*)resid)[gbase];
      s0 = b2f((u16)yv[0]) + biasv.x + xv.x;
      s1 = b2f((u16)yv[1]) + biasv.y + xv.y;
      s2 = b2f((u16)yv[2]) + biasv.z + xv.z;
      s3 = b2f((u16)yv[3]) + biasv.w + xv.w;
    } else {
      bh4 xv = *(const bh4*)&((const u16*)resid)[gbase];
      s0 = b2f((u16)yv[0]) + biasv.x + b2f((u16)xv[0]);
      s1 = b2f((u16)yv[1]) + biasv.y + b2f((u16)xv[1]);
      s2 = b2f((u16)yv[2]) + biasv.z + b2f((u16)xv[2]);
      s3 = b2f((u16)yv[3]) + biasv.w + b2f((u16)xv[3]);
    }
    float sum = s0 + s1 + s2 + s3;
    float sq  = s0*s0 + s1*s1 + s2*s2 + s3*s3;
#pragma unroll
    for (int msk = 1; msk <= 32; msk <<= 1) {
      sum += __shfl_xor(sum, msk);
      sq  += __shfl_xor(sq, msk);
    }
    float mean = sum * 0.00390625f;
    float var  = sq  * 0.00390625f - mean*mean;
    float rs = rsqrtf(var + 1e-6f);
    float o0 = (s0 - mean)*rs*gv.x + bv.x;
    float o1 = (s1 - mean)*rs*gv.y + bv.y;
    float o2 = (s2 - mean)*rs*gv.z + bv.z;
    float o3 = (s3 - mean)*rs*gv.w + bv.w;
    if constexpr (OF32) {
      float4 o = {o0, o1, o2, o3};
      *(float4*)&((float*)out)[gbase] = o;
    } else {
      bh4 o;
      o[0] = (short)f2b(o0); o[1] = (short)f2b(o1);
      o[2] = (short)f2b(o2); o[3] = (short)f2b(o3);
      *(bh4*)&((u16*)out)[gbase] = o;
    }
  }
}

// ---------- attention: one block per (qblock, head, batch); no LDS ----------
// Verbatim known-good kernel.
__global__ __launch_bounds__(256) void attn_k(
    const u16* __restrict__ qw, const u16* __restrict__ kw,
    const u16* __restrict__ vtw, u16* __restrict__ ao) {
  const int qb = blockIdx.x, hh = blockIdx.y, b = blockIdx.z;
  const int tid = threadIdx.x, lane = tid & 63, wv = tid >> 6;
  const int lg = lane >> 4, ll = lane & 15;
  const int kstart = qb ? (qb - 1) * 256 : 0;
  const size_t bh_ = (size_t)(b*8 + hh);
  const u16* kg = kw  + (bh_*1024 + kstart)*32;
  const u16* vg = vtw + bh_*32*1024 + kstart;
  const u16* qg = qw  + (bh_*1024 + qb*256)*32;

  bh8 qf[4];
#pragma unroll
  for (int qi = 0; qi < 4; ++qi)
    qf[qi] = *(const bh8*)&qg[(size_t)(wv*64 + qi*16 + ll)*32 + lg*8];

  fx4 oacc[4][2] = {};
  float lsum[4] = {0.f, 0.f, 0.f, 0.f};
  const fx4 zero = {0.f, 0.f, 0.f, 0.f};

  const int ch0 = wv*2;
  const int lo_w = qb ? ch0 + 2 : 0;
  const int hi_w = qb ? ch0 + 9 : ch0 + 1;

  for (int ohm = lo_w; ohm <= hi_w; ++ohm) {
    const int kb = ohm * 32;
    bh8 kf0 = *(const bh8*)&kg[(size_t)(kb + ll)*32 + lg*8];
    bh8 kf1 = *(const bh8*)&kg[(size_t)(kb + 16 + ll)*32 + lg*8];
    s4 vb[2][2];
#pragma unroll
    for (int cs = 0; cs < 2; ++cs)
#pragma unroll
      for (int dsub = 0; dsub < 2; ++dsub)
        vb[cs][dsub] = *(const s4*)&vg[(size_t)(dsub*16 + ll)*1024 + kb + cs*16 + lg*4];

#pragma unroll
    for (int qi = 0; qi < 4; ++qi) {
      const int ch = ch0 + (qi >> 1);
      const int dlo = qb ? ch + 2 : 0;
      const int dhi = qb ? ch + 8 : ch;
      if (ohm < dlo || ohm > dhi) continue;                 // wave-uniform
      const bool diag = (ohm == dhi);

      fx4 s0 = __builtin_amdgcn_mfma_f32_16x16x32_bf16(kf0, qf[qi], zero, 0, 0, 0);
      fx4 s1 = __builtin_amdgcn_mfma_f32_16x16x32_bf16(kf1, qf[qi], zero, 0, 0, 0);

      const int cw = ll + ((qi & 1) << 4);
      float p[2][4];
      if (!qb && !diag) {
#pragma unroll
        for (int i = 0; i < 4; ++i) { p[0][i] = ex2(s0[i]); p[1][i] = ex2(s1[i]); }
      } else {
        const int off = (qb && !diag) ? 6 : 0;
        const unsigned thr = diag ? (qb ? 7u : 32u) : 13u;
#pragma unroll
        for (int cs = 0; cs < 2; ++cs) {
          const int tb = cw + off - cs*16 - lg*4;
          fx4 sv = cs ? s1 : s0;
#pragma unroll
          for (int i = 0; i < 4; ++i) {
            bool ok = (unsigned)(tb - i) < thr;
            p[cs][i] = ok ? ex2(sv[i]) : 0.f;
          }
        }
      }
      lsum[qi] += (p[0][0]+p[0][1]+p[0][2]+p[0][3]) + (p[1][0]+p[1][1]+p[1][2]+p[1][3]);

#pragma unroll
      for (int cs = 0; cs < 2; ++cs) {
        union { unsigned u[2]; s4 s; } cv;
        cv.u[0] = cvtpk(p[cs][0], p[cs][1]);
        cv.u[1] = cvtpk(p[cs][2], p[cs][3]);
#pragma unroll
        for (int dsub = 0; dsub < 2; ++dsub)
          oacc[qi][dsub] = pv_mfma(cv.s, vb[cs][dsub], oacc[qi][dsub]);
      }
    }
  }

  float rinv[4];
#pragma unroll
  for (int qi = 0; qi < 4; ++qi) {
    float v = lsum[qi];
    v += __shfl_xor(v, 16);
    v += __shfl_xor(v, 32);
    rinv[qi] = 1.0f / v;
  }

  u16* aop = ao + ((size_t)(b*1024 + qb*256))*256 + hh*32;
#pragma unroll
  for (int qi = 0; qi < 4; ++qi) {
    float rq[4];
#pragma unroll
    for (int i = 0; i < 4; ++i) rq[i] = __shfl(rinv[qi], lg*4 + i);
#pragma unroll
    for (int dsub = 0; dsub < 2; ++dsub)
#pragma unroll
      for (int i = 0; i < 4; ++i) {
        int q = wv*64 + qi*16 + lg*4 + i;
        aop[(size_t)q*256 + dsub*16 + ll] = f2b(oacc[qi][dsub][i] * rq[i]);
      }
  }
}

extern "C" void kernel_launch(void* const* d_in, const int* in_sizes, int n_in,
                              void* d_out, int out_size, void* d_ws, size_t ws_size,
                              hipStream_t stream) {
  const float* X    = (const float*)d_in[0];
  const float* Wq   = (const float*)d_in[1];
  const float* Wk   = (const float*)d_in[2];
  const float* Wv   = (const float*)d_in[3];
  const float* Wo   = (const float*)d_in[4];
  const float* ln1g = (const float*)d_in[5];
  const float* ln1b = (const float*)d_in[6];
  const float* W1   = (const float*)d_in[7];
  const float* b1   = (const float*)d_in[8];
  const float* W2   = (const float*)d_in[9];
  const float* b2   = (const float*)d_in[10];
  const float* ln2g = (const float*)d_in[11];
  const float* ln2b = (const float*)d_in[12];
  float* out = (float*)d_out;

  char* ws = (char*)d_ws;
  const size_t A = 32768ull * 256 * 2;
  u16* qws = (u16*)(ws + A);
  u16* kws = (u16*)(ws + 2*A);
  u16* vtw = (u16*)(ws + 3*A);
  u16* ao  = (u16*)(ws);          // attn out [b][l][h*32] = [32768][256]
  u16* x1b = kws;                 // LN1 out bf16
  u16* hw  = (u16*)(ws);          // relu hidden [32768][512]
  u16* WqkvT = (u16*)(ws + 4*A);
  u16* WoT = WqkvT + 196608;
  u16* W1T = WoT + 65536;
  u16* W2T = W1T + 131072;

  conv_w_k<<<2048, 256, 0, stream>>>(Wq, Wk, Wv, Wo, W1, W2, WqkvT, WoT, W1T, W2T);
  qkv_k<<<dim3(12, 128), 256, 0, stream>>>(X, WqkvT, qws, kws, vtw);
  attn_k<<<dim3(4, 8, 32), 256, 0, stream>>>(qws, kws, vtw, ao);
  gemm_ln_k<256, 1, 0, 0><<<dim3(1, 512), 256, 0, stream>>>(ao, WoT, X, nullptr, ln1g, ln1b, x1b);
  gemm_k<256, 512, 2, 0><<<dim3(4, 256), 256, 0, stream>>>(x1b, W1T, hw, nullptr, nullptr, b1);
  gemm_ln_k<512, 0, 1, 1><<<dim3(1, 512), 256, 0, stream>>>(hw, W2T, x1b, b2, ln2g, ln2b, out);
}

// Round 9
// 122.034 us; speedup vs baseline: 1.2648x; 1.2648x over previous
//
#include <hip/hip_runtime.h>

typedef unsigned short u16;
typedef __attribute__((ext_vector_type(8))) short bh8;
typedef __attribute__((ext_vector_type(4))) short s4;
typedef __attribute__((ext_vector_type(4))) short bh4;
typedef __attribute__((ext_vector_type(4))) float fx4;

__device__ __forceinline__ u16 f2b(float f) {
  union { float f; unsigned u; } v; v.f = f;
  unsigned r = v.u + 0x7fffu + ((v.u >> 16) & 1u);
  return (u16)(r >> 16);
}
__device__ __forceinline__ float b2f(u16 h) {
  union { unsigned u; float f; } v; v.u = ((unsigned)h) << 16; return v.f;
}

// fast 2^x
__device__ __forceinline__ float ex2(float x) {
#if __has_builtin(__builtin_amdgcn_exp2f)
  return __builtin_amdgcn_exp2f(x);
#else
  return __expf(x * 0.6931471805599453f);
#endif
}

// packed f32x2 -> bf16x2 (RNE, matches f2b)
__device__ __forceinline__ unsigned cvtpk(float lo, float hi) {
  unsigned r;
  asm("v_cvt_pk_bf16_f32 %0, %1, %2" : "=v"(r) : "v"(lo), "v"(hi));
  return r;
}

// 16x16x16 bf16 MFMA (K=16)
#if __has_builtin(__builtin_amdgcn_mfma_f32_16x16x16bf16_1k)
__device__ __forceinline__ fx4 pv_mfma(s4 a, s4 b, fx4 c) {
  return __builtin_amdgcn_mfma_f32_16x16x16bf16_1k(a, b, c, 0, 0, 0);
}
#else
__device__ __forceinline__ fx4 pv_mfma(s4 a, s4 b, fx4 c) {
  asm("v_mfma_f32_16x16x16_bf16 %0, %1, %2, %0" : "+v"(c) : "v"(a), "v"(b));
  return c;
}
#endif

// raw barrier with scheduling fences on BOTH sides (rule #18): prevents hipcc
// from hoisting ds_reads above the barrier (they'd read before OTHER waves'
// stages landed — own-wave vmcnt doesn't cover those) or sinking them below.
#define SBAR() do { \
  __builtin_amdgcn_sched_barrier(0); \
  __builtin_amdgcn_s_barrier(); \
  __builtin_amdgcn_sched_barrier(0); \
} while (0)

// ---------- prep: weights -> bf16, transposed to [N][K]; Wq scaled by dh^-0.5 * log2(e) ----------
__global__ __launch_bounds__(256) void conv_w_k(const float* __restrict__ Wq, const float* __restrict__ Wk,
                         const float* __restrict__ Wv, const float* __restrict__ Wo,
                         const float* __restrict__ W1, const float* __restrict__ W2,
                         u16* __restrict__ WqkvT, u16* __restrict__ WoT,
                         u16* __restrict__ W1T, u16* __restrict__ W2T) {
  int i = blockIdx.x * 256 + threadIdx.x;
  if (i < 196608) {                       // WqkvT [768][256]
    int n = i >> 8, k = i & 255; float v;
    if (n < 256) v = Wq[k*256+n] * 0.25503487359f;   // 1/sqrt(32) * log2(e)
    else if (n < 512) v = Wk[k*256+(n-256)];
    else v = Wv[k*256+(n-512)];
    WqkvT[i] = f2b(v);
  } else if (i < 262144) {                // WoT [256][256]
    int j = i - 196608; int n = j >> 8, k = j & 255;
    WoT[j] = f2b(Wo[k*256+n]);
  } else if (i < 393216) {                // W1T [512][256]
    int j = i - 262144; int n = j >> 8, k = j & 255;
    W1T[j] = f2b(W1[k*512+n]);
  } else {                                // W2T [256][512]
    int j = i - 393216; int n = j >> 9, k = j & 511;
    W2T[j] = f2b(W2[k*256+n]);
  }
}

// ---------- GEMM: C[M][N] = A[M][K] * BT[N][K]^T, bf16 in, fp32 acc ----------
// EPI 0: scatter q/k/v  2: +bias, relu
// R8: R3 geometry EXACTLY (128x128 tile, 2 buffers, 32/48KB LDS) + counted-
// vmcnt 2-barrier K-loop (T4) with SBAR fences. __syncthreads drained the
// JUST-ISSUED stage every step (~300-900cy exposed); now the wait covers only
// the tile issued one full compute phase ago. R4 raced (no fences); R5 was
// confounded (3-buf 72KB occupancy loss). This is the clean cell.
// Hazards: barrier1 after vmcnt(LPI) => all waves' prev-tile loads landed
// before any read; barrier2 after MFMA (which forces lgkmcnt on ds_reads)
// => all reads of buf[cur] done before next iter stages into it.
// LPI exact: AF32 4A+2B=6, bf16 2A+2B=4.
// AF32=1: A is f32 staged RAW via global_load_lds; f32->bf16 at LDS-read
// time via cvt_pk; A source XOR-pre-swizzled (rule #21), conflict-free read.
template<int K, int N, int EPI, int AF32>
__global__ __launch_bounds__(256) void gemm_k(
    const void* __restrict__ Av, const u16* __restrict__ BT,
    u16* __restrict__ C0, u16* __restrict__ C1, u16* __restrict__ C2,
    const float* __restrict__ bias) {
  constexpr int BK = 32;
  constexpr int ABUF = AF32 ? 8192 : 4096;   // per-buf A stride (u16)
  constexpr int BOFF = AF32 ? 16384 : 8192;  // B region base (u16)
  constexpr int LPI  = AF32 ? 6 : 4;         // global_load_lds per thread per stage
  __shared__ u16 smem[AF32 ? 24576 : 16384];
  const int nx = gridDim.x;
  const int lid = blockIdx.y * nx + blockIdx.x;
  const int xcd = lid & 7;
  const int jj2 = lid >> 3;
  const int m0 = (xcd * (gridDim.y >> 3) + jj2 / nx) * 128;
  const int n0 = (jj2 % nx) * 128;
  const int tid = threadIdx.x, lane = tid & 63, wv = tid >> 6;
  const int wr = wv >> 1, wc = wv & 1, lg = lane >> 4, ll = lane & 15;
  const u16* A16 = (const u16*)Av;
  const float* A32 = (const float*)Av;

  fx4 acc[4][4] = {};

  auto stageB = [&](int buf, int ks) {
#pragma unroll
    for (int i = 0; i < 2; ++i) {
      int c = i*256 + tid;
      int row = c >> 2, ko = (c & 3) * 8;
      const u16* gpB = BT + (size_t)(n0+row)*K + ks + ko;
      int lbase = BOFF + buf*4096 + (i*256 + wv*64) * 8;
      __builtin_amdgcn_global_load_lds((const __attribute__((address_space(1))) void*)gpB,
          (__attribute__((address_space(3))) void*)&smem[lbase], 16, 0, 0);
    }
  };
  auto stageA16 = [&](int buf, int ks) {
#pragma unroll
    for (int i = 0; i < 2; ++i) {
      int c = i*256 + tid;
      int row = c >> 2, ko = (c & 3) * 8;
      const u16* gpA = A16 + (size_t)(m0+row)*K + ks + ko;
      int lbase = buf*ABUF + (i*256 + wv*64) * 8;
      __builtin_amdgcn_global_load_lds((const __attribute__((address_space(1))) void*)gpA,
          (__attribute__((address_space(3))) void*)&smem[lbase], 16, 0, 0);
    }
  };
  // A f32 tile: 128 rows x 32 f32 (128B/row) = 16KB = 1024 16B chunks, 4/thread.
  // LDS linear; global source pre-swizzled: logical byte = physical ^ ((row&7)<<4).
  auto stageA32 = [&](int buf, int ks) {
#pragma unroll
    for (int i = 0; i < 4; ++i) {
      int c = i*256 + tid;
      int r = c >> 3;
      int po = (c & 7) * 16;                 // physical byte offset within row
      int lo = po ^ ((r & 7) << 4);          // logical (source) byte offset
      const float* gpA = A32 + (size_t)(m0 + r)*K + ks + (lo >> 2);
      int lbase = buf*ABUF + (i*256 + wv*64) * 8;     // u16 idx; chunk = 16B
      __builtin_amdgcn_global_load_lds((const __attribute__((address_space(1))) void*)gpA,
          (__attribute__((address_space(3))) void*)&smem[lbase], 16, 0, 0);
    }
  };

  constexpr int NT = K / BK;
  if constexpr (AF32) stageA32(0, 0); else stageA16(0, 0);
  stageB(0, 0);
  int cur = 0;
  for (int t = 0; t < NT; ++t) {
    if (t + 1 < NT) {
      if constexpr (AF32) stageA32(cur ^ 1, (t+1)*BK); else stageA16(cur ^ 1, (t+1)*BK);
      stageB(cur ^ 1, (t+1)*BK);
      asm volatile("s_waitcnt vmcnt(%0)" :: "i"(LPI) : "memory");  // prev-tile loads landed
    } else {
      asm volatile("s_waitcnt vmcnt(0)" ::: "memory");
    }
    SBAR();                                 // ALL waves' buf[cur] is in LDS
    bh8 af[4], bfr[4];
    if constexpr (AF32) {
#pragma unroll
      for (int mi = 0; mi < 4; ++mi) {
        int r = wr*64 + mi*16 + ll;
        int sw = (r & 7) << 4;
        int b0 = r*128 + ((lg*32) ^ sw);
        int b1 = r*128 + ((lg*32 + 16) ^ sw);
        float4 a0 = *(const float4*)&smem[cur*ABUF + (b0 >> 1)];
        float4 a1 = *(const float4*)&smem[cur*ABUF + (b1 >> 1)];
        union { unsigned u[4]; bh8 v; } cvt;
        cvt.u[0] = cvtpk(a0.x, a0.y); cvt.u[1] = cvtpk(a0.z, a0.w);
        cvt.u[2] = cvtpk(a1.x, a1.y); cvt.u[3] = cvtpk(a1.z, a1.w);
        af[mi] = cvt.v;
      }
    } else {
#pragma unroll
      for (int mi = 0; mi < 4; ++mi)
        af[mi] = *(const bh8*)&smem[cur*ABUF + (wr*64 + mi*16 + ll)*BK + lg*8];
    }
#pragma unroll
    for (int ni = 0; ni < 4; ++ni)
      bfr[ni] = *(const bh8*)&smem[BOFF + cur*4096 + (wc*64 + ni*16 + ll)*BK + lg*8];
#pragma unroll
    for (int mi = 0; mi < 4; ++mi)
#pragma unroll
      for (int ni = 0; ni < 4; ++ni)
        acc[mi][ni] = __builtin_amdgcn_mfma_f32_16x16x32_bf16(af[mi], bfr[ni], acc[mi][ni], 0, 0, 0);
    SBAR();                                 // all waves done reading buf[cur] (WAR)
    cur ^= 1;
  }
  __syncthreads();                          // quiesce before C-tile aliases staging LDS

  // ---- epilogue: acc -> LDS (swizzled) -> coalesced 16B stores ----
  auto swz = [](int r) { return ((r & 14) << 2) ^ ((r & 3) << 5); };
  const bool vt = (EPI == 0) && (n0 >= 512);     // vT output blocks

  if (!vt) {
    float bv[4];
    if constexpr (EPI >= 2) {
#pragma unroll
      for (int ni = 0; ni < 4; ++ni) bv[ni] = bias[n0 + wc*64 + ni*16 + ll];
    }
#pragma unroll
    for (int mi = 0; mi < 4; ++mi)
#pragma unroll
      for (int ni = 0; ni < 4; ++ni) {
        fx4 v = acc[mi][ni];
        int n = wc*64 + ni*16 + ll;
#pragma unroll
        for (int ii = 0; ii < 2; ++ii) {
          float x0 = v[2*ii], x1 = v[2*ii+1];
          if constexpr (EPI == 2) { x0 = fmaxf(x0 + bv[ni], 0.f); x1 = fmaxf(x1 + bv[ni], 0.f); }
          unsigned pk = cvtpk(x0, x1);
          int mA = wr*64 + mi*16 + lg*4 + 2*ii;
          int mB = mA + 1;
          smem[mA*128 + (n ^ swz(mA))] = (u16)pk;
          smem[mB*128 + (n ^ swz(mB))] = (u16)(pk >> 16);
        }
      }
  } else {
    // transposed staging: LDS[n][m ^ swz(n)]
#pragma unroll
    for (int mi = 0; mi < 4; ++mi)
#pragma unroll
      for (int ni = 0; ni < 4; ++ni) {
        fx4 v = acc[mi][ni];
        int n = wc*64 + ni*16 + ll;
        int mb = wr*64 + mi*16 + lg*4;
        uint2 pk;
        pk.x = cvtpk(v[0], v[1]);
        pk.y = cvtpk(v[2], v[3]);
        *(uint2*)&smem[n*128 + (mb ^ swz(n))] = pk;
      }
  }
  __syncthreads();

#pragma unroll
  for (int j = 0; j < 8; ++j) {
    int cid = tid + 256*j;
    int row = cid >> 4, c8 = (cid & 15) << 3;
    bh8 val = *(const bh8*)&smem[row*128 + (c8 ^ swz(row))];
    if constexpr (EPI == 0) {
      if (!vt) {                                   // q/k: [b][h][l][32]
        int m = m0 + row; int b = m >> 10, l = m & 1023;
        int n = n0 + c8; int hh = (n >> 5) & 7, d = n & 31;
        size_t bh_ = (size_t)(b*8 + hh);
        u16* dst = (n0 < 256) ? C0 : C1;
        *(bh8*)&dst[(bh_*1024 + l)*32 + d] = val;
      } else {                                     // vT: [b][h][32][1024]
        int n = n0 + row; int hh = (n >> 5) & 7, d = n & 31;
        int m = m0 + c8; int b = m >> 10, l = m & 1023;
        size_t bh_ = (size_t)(b*8 + hh);
        *(bh8*)&C2[(bh_*32 + d)*1024 + l] = val;
      }
    } else {
      *(bh8*)&C0[(size_t)(m0+row)*N + n0 + c8] = val;
    }
  }
}

// ---------- fused GEMM + residual + LayerNorm ----------
// C = A[M][K] * BT[256][K]^T (+bias); out = LN(C + resid) row-wise.
// R3 geometry; same counted-vmcnt 2-barrier K-loop (LPI = 1A + 4B = 5).
template<int K, int RF32, int OF32, int BIAS>
__global__ __launch_bounds__(256) void gemm_ln_k(
    const u16* __restrict__ A, const u16* __restrict__ BT,
    const void* __restrict__ resid, const float* __restrict__ bias,
    const float* __restrict__ g, const float* __restrict__ b,
    void* __restrict__ out) {
  constexpr int BK = 32;
  constexpr int LPI = 5;
  __shared__ u16 smem[20480];   // A dbuf [2][2048) @0, B dbuf [2][8192) @4096; C tile [64][256] @0
  const int lid = blockIdx.y;
  const int xcd = lid & 7;
  const int jj2 = lid >> 3;
  const int m0 = (xcd * (gridDim.y >> 3) + jj2) * 64;
  const int tid = threadIdx.x, lane = tid & 63, wv = tid >> 6;
  const int wr = wv >> 1, wc = wv & 1, lg = lane >> 4, ll = lane & 15;

  fx4 acc[2][8] = {};

  auto stage = [&](int buf, int ks) {
    {
      int c = tid;
      int row = c >> 2, ko = (c & 3) * 8;
      const u16* gpA = A + (size_t)(m0+row)*K + ks + ko;
      int lbase = wv*512;
      __builtin_amdgcn_global_load_lds((const __attribute__((address_space(1))) void*)gpA,
          (__attribute__((address_space(3))) void*)&smem[buf*2048 + lbase], 16, 0, 0);
    }
#pragma unroll
    for (int i = 0; i < 4; ++i) {
      int c = i*256 + tid;
      int row = c >> 2, ko = (c & 3) * 8;
      const u16* gpB = BT + (size_t)row*K + ks + ko;
      int lbase = (i*256 + wv*64) * 8;
      __builtin_amdgcn_global_load_lds((const __attribute__((address_space(1))) void*)gpB,
          (__attribute__((address_space(3))) void*)&smem[4096 + buf*8192 + lbase], 16, 0, 0);
    }
  };

  constexpr int NT = K / BK;
  stage(0, 0);
  int cur = 0;
  for (int t = 0; t < NT; ++t) {
    if (t + 1 < NT) {
      stage(cur ^ 1, (t+1)*BK);
      asm volatile("s_waitcnt vmcnt(%0)" :: "i"(LPI) : "memory");
    } else {
      asm volatile("s_waitcnt vmcnt(0)" ::: "memory");
    }
    SBAR();
    bh8 af[2], bfr[8];
#pragma unroll
    for (int mi = 0; mi < 2; ++mi)
      af[mi] = *(const bh8*)&smem[cur*2048 + (wr*32 + mi*16 + ll)*BK + lg*8];
#pragma unroll
    for (int ni = 0; ni < 8; ++ni)
      bfr[ni] = *(const bh8*)&smem[4096 + cur*8192 + (wc*128 + ni*16 + ll)*BK + lg*8];
#pragma unroll
    for (int mi = 0; mi < 2; ++mi)
#pragma unroll
      for (int ni = 0; ni < 8; ++ni)
        acc[mi][ni] = __builtin_amdgcn_mfma_f32_16x16x32_bf16(bfr[ni], af[mi], acc[mi][ni], 0, 0, 0);
    SBAR();
    cur ^= 1;
  }
  __syncthreads();              // quiesce before C-tile aliases staging LDS

  // stage C tile: row m_l = wr*32+mi*16+ll, cols n_l..n_l+3 = wc*128+ni*16+lg*4
#pragma unroll
  for (int mi = 0; mi < 2; ++mi) {
    int m_l = wr*32 + mi*16 + ll;
    int sx = (m_l & 7) << 1;
#pragma unroll
    for (int ni = 0; ni < 8; ++ni) {
      fx4 v = acc[mi][ni];
      int gidx = (wc*32 + ni*4 + lg) ^ sx;
      uint2 pk;
      pk.x = cvtpk(v[0], v[1]);
      pk.y = cvtpk(v[2], v[3]);
      *(uint2*)&smem[m_l*256 + gidx*4] = pk;
    }
  }
  __syncthreads();

  // per-row LN: wave wv handles rows wv*16 .. wv*16+15; lane covers cols lane*4..+3
  const int c0 = lane * 4;
  float4 gv = *(const float4*)&g[c0];
  float4 bv = *(const float4*)&b[c0];
  float4 biasv = {0.f, 0.f, 0.f, 0.f};
  if constexpr (BIAS) biasv = *(const float4*)&bias[c0];
#pragma unroll 4
  for (int rr = 0; rr < 16; ++rr) {
    int r = wv*16 + rr;
    bh4 yv = *(const bh4*)&smem[r*256 + ((lane ^ ((r & 7) << 1)) << 2)];
    size_t gbase = (size_t)(m0 + r) * 256 + c0;
    float s0, s1, s2, s3;
    if constexpr (RF32) {
      float4 xv = *(const float4*)&((const float*)resid)[gbase];
      s0 = b2f((u16)yv[0]) + biasv.x + xv.x;
      s1 = b2f((u16)yv[1]) + biasv.y + xv.y;
      s2 = b2f((u16)yv[2]) + biasv.z + xv.z;
      s3 = b2f((u16)yv[3]) + biasv.w + xv.w;
    } else {
      bh4 xv = *(const bh4*)&((const u16*)resid)[gbase];
      s0 = b2f((u16)yv[0]) + biasv.x + b2f((u16)xv[0]);
      s1 = b2f((u16)yv[1]) + biasv.y + b2f((u16)xv[1]);
      s2 = b2f((u16)yv[2]) + biasv.z + b2f((u16)xv[2]);
      s3 = b2f((u16)yv[3]) + biasv.w + b2f((u16)xv[3]);
    }
    float sum = s0 + s1 + s2 + s3;
    float sq  = s0*s0 + s1*s1 + s2*s2 + s3*s3;
#pragma unroll
    for (int msk = 1; msk <= 32; msk <<= 1) {
      sum += __shfl_xor(sum, msk);
      sq  += __shfl_xor(sq, msk);
    }
    float mean = sum * 0.00390625f;
    float var  = sq  * 0.00390625f - mean*mean;
    float rs = rsqrtf(var + 1e-6f);
    float o0 = (s0 - mean)*rs*gv.x + bv.x;
    float o1 = (s1 - mean)*rs*gv.y + bv.y;
    float o2 = (s2 - mean)*rs*gv.z + bv.z;
    float o3 = (s3 - mean)*rs*gv.w + bv.w;
    if constexpr (OF32) {
      float4 o = {o0, o1, o2, o3};
      *(float4*)&((float*)out)[gbase] = o;
    } else {
      bh4 o;
      o[0] = (short)f2b(o0); o[1] = (short)f2b(o1);
      o[2] = (short)f2b(o2); o[3] = (short)f2b(o3);
      *(bh4*)&((u16*)out)[gbase] = o;
    }
  }
}

// ---------- attention: one block per (qblock, head, batch); no LDS ----------
// Verbatim known-good kernel.
__global__ __launch_bounds__(256) void attn_k(
    const u16* __restrict__ qw, const u16* __restrict__ kw,
    const u16* __restrict__ vtw, u16* __restrict__ ao) {
  const int qb = blockIdx.x, hh = blockIdx.y, b = blockIdx.z;
  const int tid = threadIdx.x, lane = tid & 63, wv = tid >> 6;
  const int lg = lane >> 4, ll = lane & 15;
  const int kstart = qb ? (qb - 1) * 256 : 0;
  const size_t bh_ = (size_t)(b*8 + hh);
  const u16* kg = kw  + (bh_*1024 + kstart)*32;
  const u16* vg = vtw + bh_*32*1024 + kstart;
  const u16* qg = qw  + (bh_*1024 + qb*256)*32;

  bh8 qf[4];
#pragma unroll
  for (int qi = 0; qi < 4; ++qi)
    qf[qi] = *(const bh8*)&qg[(size_t)(wv*64 + qi*16 + ll)*32 + lg*8];

  fx4 oacc[4][2] = {};
  float lsum[4] = {0.f, 0.f, 0.f, 0.f};
  const fx4 zero = {0.f, 0.f, 0.f, 0.f};

  const int ch0 = wv*2;
  const int lo_w = qb ? ch0 + 2 : 0;
  const int hi_w = qb ? ch0 + 9 : ch0 + 1;

  for (int ohm = lo_w; ohm <= hi_w; ++ohm) {
    const int kb = ohm * 32;
    bh8 kf0 = *(const bh8*)&kg[(size_t)(kb + ll)*32 + lg*8];
    bh8 kf1 = *(const bh8*)&kg[(size_t)(kb + 16 + ll)*32 + lg*8];
    s4 vb[2][2];
#pragma unroll
    for (int cs = 0; cs < 2; ++cs)
#pragma unroll
      for (int dsub = 0; dsub < 2; ++dsub)
        vb[cs][dsub] = *(const s4*)&vg[(size_t)(dsub*16 + ll)*1024 + kb + cs*16 + lg*4];

#pragma unroll
    for (int qi = 0; qi < 4; ++qi) {
      const int ch = ch0 + (qi >> 1);
      const int dlo = qb ? ch + 2 : 0;
      const int dhi = qb ? ch + 8 : ch;
      if (ohm < dlo || ohm > dhi) continue;                 // wave-uniform
      const bool diag = (ohm == dhi);

      fx4 s0 = __builtin_amdgcn_mfma_f32_16x16x32_bf16(kf0, qf[qi], zero, 0, 0, 0);
      fx4 s1 = __builtin_amdgcn_mfma_f32_16x16x32_bf16(kf1, qf[qi], zero, 0, 0, 0);

      const int cw = ll + ((qi & 1) << 4);
      float p[2][4];
      if (!qb && !diag) {
#pragma unroll
        for (int i = 0; i < 4; ++i) { p[0][i] = ex2(s0[i]); p[1][i] = ex2(s1[i]); }
      } else {
        const int off = (qb && !diag) ? 6 : 0;
        const unsigned thr = diag ? (qb ? 7u : 32u) : 13u;
#pragma unroll
        for (int cs = 0; cs < 2; ++cs) {
          const int tb = cw + off - cs*16 - lg*4;
          fx4 sv = cs ? s1 : s0;
#pragma unroll
          for (int i = 0; i < 4; ++i) {
            bool ok = (unsigned)(tb - i) < thr;
            p[cs][i] = ok ? ex2(sv[i]) : 0.f;
          }
        }
      }
      lsum[qi] += (p[0][0]+p[0][1]+p[0][2]+p[0][3]) + (p[1][0]+p[1][1]+p[1][2]+p[1][3]);

#pragma unroll
      for (int cs = 0; cs < 2; ++cs) {
        union { unsigned u[2]; s4 s; } cv;
        cv.u[0] = cvtpk(p[cs][0], p[cs][1]);
        cv.u[1] = cvtpk(p[cs][2], p[cs][3]);
#pragma unroll
        for (int dsub = 0; dsub < 2; ++dsub)
          oacc[qi][dsub] = pv_mfma(cv.s, vb[cs][dsub], oacc[qi][dsub]);
      }
    }
  }

  float rinv[4];
#pragma unroll
  for (int qi = 0; qi < 4; ++qi) {
    float v = lsum[qi];
    v += __shfl_xor(v, 16);
    v += __shfl_xor(v, 32);
    rinv[qi] = 1.0f / v;
  }

  u16* aop = ao + ((size_t)(b*1024 + qb*256))*256 + hh*32;
#pragma unroll
  for (int qi = 0; qi < 4; ++qi) {
    float rq[4];
#pragma unroll
    for (int i = 0; i < 4; ++i) rq[i] = __shfl(rinv[qi], lg*4 + i);
#pragma unroll
    for (int dsub = 0; dsub < 2; ++dsub)
#pragma unroll
      for (int i = 0; i < 4; ++i) {
        int q = wv*64 + qi*16 + lg*4 + i;
        aop[(size_t)q*256 + dsub*16 + ll] = f2b(oacc[qi][dsub][i] * rq[i]);
      }
  }
}

extern "C" void kernel_launch(void* const* d_in, const int* in_sizes, int n_in,
                              void* d_out, int out_size, void* d_ws, size_t ws_size,
                              hipStream_t stream) {
  const float* X    = (const float*)d_in[0];
  const float* Wq   = (const float*)d_in[1];
  const float* Wk   = (const float*)d_in[2];
  const float* Wv   = (const float*)d_in[3];
  const float* Wo   = (const float*)d_in[4];
  const float* ln1g = (const float*)d_in[5];
  const float* ln1b = (const float*)d_in[6];
  const float* W1   = (const float*)d_in[7];
  const float* b1   = (const float*)d_in[8];
  const float* W2   = (const float*)d_in[9];
  const float* b2   = (const float*)d_in[10];
  const float* ln2g = (const float*)d_in[11];
  const float* ln2b = (const float*)d_in[12];
  float* out = (float*)d_out;

  char* ws = (char*)d_ws;
  const size_t A = 32768ull * 256 * 2;
  u16* qws = (u16*)(ws + A);
  u16* kws = (u16*)(ws + 2*A);
  u16* vtw = (u16*)(ws + 3*A);
  u16* ao  = (u16*)(ws);          // attn out [b][l][h*32] = [32768][256]
  u16* x1b = kws;                 // LN1 out bf16
  u16* hw  = (u16*)(ws);          // relu hidden [32768][512]
  u16* WqkvT = (u16*)(ws + 4*A);
  u16* WoT = WqkvT + 196608;
  u16* W1T = WoT + 65536;
  u16* W2T = W1T + 131072;

  conv_w_k<<<2048, 256, 0, stream>>>(Wq, Wk, Wv, Wo, W1, W2, WqkvT, WoT, W1T, W2T);
  gemm_k<256, 768, 0, 1><<<dim3(6, 256), 256, 0, stream>>>(X, WqkvT, qws, kws, vtw, nullptr);
  attn_k<<<dim3(4, 8, 32), 256, 0, stream>>>(qws, kws, vtw, ao);
  gemm_ln_k<256, 1, 0, 0><<<dim3(1, 512), 256, 0, stream>>>(ao, WoT, X, nullptr, ln1g, ln1b, x1b);
  gemm_k<256, 512, 2, 0><<<dim3(4, 256), 256, 0, stream>>>(x1b, W1T, hw, nullptr, nullptr, b1);
  gemm_ln_k<512, 0, 1, 1><<<dim3(1, 512), 256, 0, stream>>>(hw, W2T, x1b, b2, ln2g, ln2b, out);
}

// Round 10
// 120.981 us; speedup vs baseline: 1.2758x; 1.0087x over previous
//
#include <hip/hip_runtime.h>

typedef unsigned short u16;
typedef __attribute__((ext_vector_type(8))) short bh8;
typedef __attribute__((ext_vector_type(4))) short s4;
typedef __attribute__((ext_vector_type(4))) short bh4;
typedef __attribute__((ext_vector_type(4))) float fx4;

__device__ __forceinline__ u16 f2b(float f) {
  union { float f; unsigned u; } v; v.f = f;
  unsigned r = v.u + 0x7fffu + ((v.u >> 16) & 1u);
  return (u16)(r >> 16);
}
__device__ __forceinline__ float b2f(u16 h) {
  union { unsigned u; float f; } v; v.u = ((unsigned)h) << 16; return v.f;
}

// fast 2^x
__device__ __forceinline__ float ex2(float x) {
#if __has_builtin(__builtin_amdgcn_exp2f)
  return __builtin_amdgcn_exp2f(x);
#else
  return __expf(x * 0.6931471805599453f);
#endif
}

// packed f32x2 -> bf16x2 (RNE, matches f2b)
__device__ __forceinline__ unsigned cvtpk(float lo, float hi) {
  unsigned r;
  asm("v_cvt_pk_bf16_f32 %0, %1, %2" : "=v"(r) : "v"(lo), "v"(hi));
  return r;
}

// 16x16x16 bf16 MFMA (K=16)
#if __has_builtin(__builtin_amdgcn_mfma_f32_16x16x16bf16_1k)
__device__ __forceinline__ fx4 pv_mfma(s4 a, s4 b, fx4 c) {
  return __builtin_amdgcn_mfma_f32_16x16x16bf16_1k(a, b, c, 0, 0, 0);
}
#else
__device__ __forceinline__ fx4 pv_mfma(s4 a, s4 b, fx4 c) {
  asm("v_mfma_f32_16x16x16_bf16 %0, %1, %2, %0" : "+v"(c) : "v"(a), "v"(b));
  return c;
}
#endif

// raw barrier with scheduling fences on BOTH sides (rule #18): prevents hipcc
// from hoisting ds_reads above the barrier or sinking them below it.
#define SBAR() do { \
  __builtin_amdgcn_sched_barrier(0); \
  __builtin_amdgcn_s_barrier(); \
  __builtin_amdgcn_sched_barrier(0); \
} while (0)

// ---------- prep: weights -> bf16, transposed to [N][K]; Wq scaled by dh^-0.5 * log2(e) ----------
__global__ __launch_bounds__(256) void conv_w_k(const float* __restrict__ Wq, const float* __restrict__ Wk,
                         const float* __restrict__ Wv, const float* __restrict__ Wo,
                         const float* __restrict__ W1, const float* __restrict__ W2,
                         u16* __restrict__ WqkvT, u16* __restrict__ WoT,
                         u16* __restrict__ W1T, u16* __restrict__ W2T) {
  int i = blockIdx.x * 256 + threadIdx.x;
  if (i < 196608) {                       // WqkvT [768][256]
    int n = i >> 8, k = i & 255; float v;
    if (n < 256) v = Wq[k*256+n] * 0.25503487359f;   // 1/sqrt(32) * log2(e)
    else if (n < 512) v = Wk[k*256+(n-256)];
    else v = Wv[k*256+(n-512)];
    WqkvT[i] = f2b(v);
  } else if (i < 262144) {                // WoT [256][256]
    int j = i - 196608; int n = j >> 8, k = j & 255;
    WoT[j] = f2b(Wo[k*256+n]);
  } else if (i < 393216) {                // W1T [512][256]
    int j = i - 262144; int n = j >> 8, k = j & 255;
    W1T[j] = f2b(W1[k*512+n]);
  } else {                                // W2T [256][512]
    int j = i - 393216; int n = j >> 9, k = j & 511;
    W2T[j] = f2b(W2[k*256+n]);
  }
}

// ---------- GEMM: C[M][N] = A[M][K] * BT[N][K]^T, bf16 in, fp32 acc ----------
// EPI 0: scatter q/k/v  2: +bias, relu
// R9 assembly of measured-best variants:
//  * AF32 (QKV): counted-vmcnt 2-barrier loop w/ SBAR fences (R8: 41.4us, its
//    best). vmcnt(6)=prev-tile loads landed, this tile's 6 stay in flight.
//  * bf16 (W1): plain __syncthreads 2-phase loop (R3: best total).
// AF32=1: A is f32 staged RAW via global_load_lds; f32->bf16 at LDS-read
// time via cvt_pk; A source XOR-pre-swizzled (rule #21), conflict-free read.
template<int K, int N, int EPI, int AF32>
__global__ __launch_bounds__(256) void gemm_k(
    const void* __restrict__ Av, const u16* __restrict__ BT,
    u16* __restrict__ C0, u16* __restrict__ C1, u16* __restrict__ C2,
    const float* __restrict__ bias) {
  constexpr int BK = 32;
  constexpr int ABUF = AF32 ? 8192 : 4096;   // per-buf A stride (u16)
  constexpr int BOFF = AF32 ? 16384 : 8192;  // B region base (u16)
  __shared__ u16 smem[AF32 ? 24576 : 16384];
  const int nx = gridDim.x;
  const int lid = blockIdx.y * nx + blockIdx.x;
  const int xcd = lid & 7;
  const int jj2 = lid >> 3;
  const int m0 = (xcd * (gridDim.y >> 3) + jj2 / nx) * 128;
  const int n0 = (jj2 % nx) * 128;
  const int tid = threadIdx.x, lane = tid & 63, wv = tid >> 6;
  const int wr = wv >> 1, wc = wv & 1, lg = lane >> 4, ll = lane & 15;
  const u16* A16 = (const u16*)Av;
  const float* A32 = (const float*)Av;

  fx4 acc[4][4] = {};

  auto stageB = [&](int buf, int ks) {
#pragma unroll
    for (int i = 0; i < 2; ++i) {
      int c = i*256 + tid;
      int row = c >> 2, ko = (c & 3) * 8;
      const u16* gpB = BT + (size_t)(n0+row)*K + ks + ko;
      int lbase = BOFF + buf*4096 + (i*256 + wv*64) * 8;
      __builtin_amdgcn_global_load_lds((const __attribute__((address_space(1))) void*)gpB,
          (__attribute__((address_space(3))) void*)&smem[lbase], 16, 0, 0);
    }
  };
  auto stageA16 = [&](int buf, int ks) {
#pragma unroll
    for (int i = 0; i < 2; ++i) {
      int c = i*256 + tid;
      int row = c >> 2, ko = (c & 3) * 8;
      const u16* gpA = A16 + (size_t)(m0+row)*K + ks + ko;
      int lbase = buf*ABUF + (i*256 + wv*64) * 8;
      __builtin_amdgcn_global_load_lds((const __attribute__((address_space(1))) void*)gpA,
          (__attribute__((address_space(3))) void*)&smem[lbase], 16, 0, 0);
    }
  };
  // A f32 tile: 128 rows x 32 f32 (128B/row) = 16KB = 1024 16B chunks, 4/thread.
  // LDS linear; global source pre-swizzled: logical byte = physical ^ ((row&7)<<4).
  auto stageA32 = [&](int buf, int ks) {
#pragma unroll
    for (int i = 0; i < 4; ++i) {
      int c = i*256 + tid;
      int r = c >> 3;
      int po = (c & 7) * 16;                 // physical byte offset within row
      int lo = po ^ ((r & 7) << 4);          // logical (source) byte offset
      const float* gpA = A32 + (size_t)(m0 + r)*K + ks + (lo >> 2);
      int lbase = buf*ABUF + (i*256 + wv*64) * 8;     // u16 idx; chunk = 16B
      __builtin_amdgcn_global_load_lds((const __attribute__((address_space(1))) void*)gpA,
          (__attribute__((address_space(3))) void*)&smem[lbase], 16, 0, 0);
    }
  };

  constexpr int NT = K / BK;
  if constexpr (AF32) stageA32(0, 0); else stageA16(0, 0);
  stageB(0, 0);
  if constexpr (!AF32) __syncthreads();
  int cur = 0;
  for (int t = 0; t < NT; ++t) {
    if constexpr (AF32) {
      if (t + 1 < NT) {
        stageA32(cur ^ 1, (t+1)*BK);
        stageB(cur ^ 1, (t+1)*BK);
        asm volatile("s_waitcnt vmcnt(6)" ::: "memory");   // prev-tile loads landed
      } else {
        asm volatile("s_waitcnt vmcnt(0)" ::: "memory");
      }
      SBAR();                               // ALL waves' buf[cur] is in LDS
    } else {
      if (t + 1 < NT) {
        stageA16(cur ^ 1, (t+1)*BK);
        stageB(cur ^ 1, (t+1)*BK);
      }
    }
    bh8 af[4], bfr[4];
    if constexpr (AF32) {
#pragma unroll
      for (int mi = 0; mi < 4; ++mi) {
        int r = wr*64 + mi*16 + ll;
        int sw = (r & 7) << 4;
        int b0 = r*128 + ((lg*32) ^ sw);
        int b1 = r*128 + ((lg*32 + 16) ^ sw);
        float4 a0 = *(const float4*)&smem[cur*ABUF + (b0 >> 1)];
        float4 a1 = *(const float4*)&smem[cur*ABUF + (b1 >> 1)];
        union { unsigned u[4]; bh8 v; } cvt;
        cvt.u[0] = cvtpk(a0.x, a0.y); cvt.u[1] = cvtpk(a0.z, a0.w);
        cvt.u[2] = cvtpk(a1.x, a1.y); cvt.u[3] = cvtpk(a1.z, a1.w);
        af[mi] = cvt.v;
      }
    } else {
#pragma unroll
      for (int mi = 0; mi < 4; ++mi)
        af[mi] = *(const bh8*)&smem[cur*ABUF + (wr*64 + mi*16 + ll)*BK + lg*8];
    }
#pragma unroll
    for (int ni = 0; ni < 4; ++ni)
      bfr[ni] = *(const bh8*)&smem[BOFF + cur*4096 + (wc*64 + ni*16 + ll)*BK + lg*8];
#pragma unroll
    for (int mi = 0; mi < 4; ++mi)
#pragma unroll
      for (int ni = 0; ni < 4; ++ni)
        acc[mi][ni] = __builtin_amdgcn_mfma_f32_16x16x32_bf16(af[mi], bfr[ni], acc[mi][ni], 0, 0, 0);
    if constexpr (AF32) SBAR(); else __syncthreads();   // WAR on buf[cur]
    cur ^= 1;
  }
  if constexpr (AF32) __syncthreads();      // quiesce before C-tile aliases staging LDS

  // ---- epilogue: acc -> LDS (swizzled) -> coalesced 16B stores ----
  auto swz = [](int r) { return ((r & 14) << 2) ^ ((r & 3) << 5); };
  const bool vt = (EPI == 0) && (n0 >= 512);     // vT output blocks

  if (!vt) {
    float bv[4];
    if constexpr (EPI >= 2) {
#pragma unroll
      for (int ni = 0; ni < 4; ++ni) bv[ni] = bias[n0 + wc*64 + ni*16 + ll];
    }
#pragma unroll
    for (int mi = 0; mi < 4; ++mi)
#pragma unroll
      for (int ni = 0; ni < 4; ++ni) {
        fx4 v = acc[mi][ni];
        int n = wc*64 + ni*16 + ll;
#pragma unroll
        for (int ii = 0; ii < 2; ++ii) {
          float x0 = v[2*ii], x1 = v[2*ii+1];
          if constexpr (EPI == 2) { x0 = fmaxf(x0 + bv[ni], 0.f); x1 = fmaxf(x1 + bv[ni], 0.f); }
          unsigned pk = cvtpk(x0, x1);
          int mA = wr*64 + mi*16 + lg*4 + 2*ii;
          int mB = mA + 1;
          smem[mA*128 + (n ^ swz(mA))] = (u16)pk;
          smem[mB*128 + (n ^ swz(mB))] = (u16)(pk >> 16);
        }
      }
  } else {
    // transposed staging: LDS[n][m ^ swz(n)]
#pragma unroll
    for (int mi = 0; mi < 4; ++mi)
#pragma unroll
      for (int ni = 0; ni < 4; ++ni) {
        fx4 v = acc[mi][ni];
        int n = wc*64 + ni*16 + ll;
        int mb = wr*64 + mi*16 + lg*4;
        uint2 pk;
        pk.x = cvtpk(v[0], v[1]);
        pk.y = cvtpk(v[2], v[3]);
        *(uint2*)&smem[n*128 + (mb ^ swz(n))] = pk;
      }
  }
  __syncthreads();

#pragma unroll
  for (int j = 0; j < 8; ++j) {
    int cid = tid + 256*j;
    int row = cid >> 4, c8 = (cid & 15) << 3;
    bh8 val = *(const bh8*)&smem[row*128 + (c8 ^ swz(row))];
    if constexpr (EPI == 0) {
      if (!vt) {                                   // q/k: [b][h][l][32]
        int m = m0 + row; int b = m >> 10, l = m & 1023;
        int n = n0 + c8; int hh = (n >> 5) & 7, d = n & 31;
        size_t bh_ = (size_t)(b*8 + hh);
        u16* dst = (n0 < 256) ? C0 : C1;
        *(bh8*)&dst[(bh_*1024 + l)*32 + d] = val;
      } else {                                     // vT: [b][h][32][1024]
        int n = n0 + row; int hh = (n >> 5) & 7, d = n & 31;
        int m = m0 + c8; int b = m >> 10, l = m & 1023;
        size_t bh_ = (size_t)(b*8 + hh);
        *(bh8*)&C2[(bh_*32 + d)*1024 + l] = val;
      }
    } else {
      *(bh8*)&C0[(size_t)(m0+row)*N + n0 + c8] = val;
    }
  }
}

// ---------- fused GEMM + residual + LayerNorm ----------
// Verbatim R3 passing version (best total): 64x256 tile, 4 waves,
// 2-buf __syncthreads K-loop.
template<int K, int RF32, int OF32, int BIAS>
__global__ __launch_bounds__(256) void gemm_ln_k(
    const u16* __restrict__ A, const u16* __restrict__ BT,
    const void* __restrict__ resid, const float* __restrict__ bias,
    const float* __restrict__ g, const float* __restrict__ b,
    void* __restrict__ out) {
  constexpr int BK = 32;
  __shared__ u16 smem[20480];   // A dbuf [2][2048) @0, B dbuf [2][8192) @4096; C tile [64][256] @0
  const int lid = blockIdx.y;
  const int xcd = lid & 7;
  const int jj2 = lid >> 3;
  const int m0 = (xcd * (gridDim.y >> 3) + jj2) * 64;
  const int tid = threadIdx.x, lane = tid & 63, wv = tid >> 6;
  const int wr = wv >> 1, wc = wv & 1, lg = lane >> 4, ll = lane & 15;

  fx4 acc[2][8] = {};

  auto stage = [&](int buf, int ks) {
    {
      int c = tid;
      int row = c >> 2, ko = (c & 3) * 8;
      const u16* gpA = A + (size_t)(m0+row)*K + ks + ko;
      int lbase = wv*512;
      __builtin_amdgcn_global_load_lds((const __attribute__((address_space(1))) void*)gpA,
          (__attribute__((address_space(3))) void*)&smem[buf*2048 + lbase], 16, 0, 0);
    }
#pragma unroll
    for (int i = 0; i < 4; ++i) {
      int c = i*256 + tid;
      int row = c >> 2, ko = (c & 3) * 8;
      const u16* gpB = BT + (size_t)row*K + ks + ko;
      int lbase = (i*256 + wv*64) * 8;
      __builtin_amdgcn_global_load_lds((const __attribute__((address_space(1))) void*)gpB,
          (__attribute__((address_space(3))) void*)&smem[4096 + buf*8192 + lbase], 16, 0, 0);
    }
  };

  constexpr int NT = K / BK;
  stage(0, 0);
  __syncthreads();
  int cur = 0;
  for (int t = 0; t < NT; ++t) {
    if (t + 1 < NT) stage(cur ^ 1, (t+1)*BK);
    bh8 af[2], bfr[8];
#pragma unroll
    for (int mi = 0; mi < 2; ++mi)
      af[mi] = *(const bh8*)&smem[cur*2048 + (wr*32 + mi*16 + ll)*BK + lg*8];
#pragma unroll
    for (int ni = 0; ni < 8; ++ni)
      bfr[ni] = *(const bh8*)&smem[4096 + cur*8192 + (wc*128 + ni*16 + ll)*BK + lg*8];
#pragma unroll
    for (int mi = 0; mi < 2; ++mi)
#pragma unroll
      for (int ni = 0; ni < 8; ++ni)
        acc[mi][ni] = __builtin_amdgcn_mfma_f32_16x16x32_bf16(bfr[ni], af[mi], acc[mi][ni], 0, 0, 0);
    __syncthreads();
    cur ^= 1;
  }

  // stage C tile: row m_l = wr*32+mi*16+ll, cols n_l..n_l+3 = wc*128+ni*16+lg*4
#pragma unroll
  for (int mi = 0; mi < 2; ++mi) {
    int m_l = wr*32 + mi*16 + ll;
    int sx = (m_l & 7) << 1;
#pragma unroll
    for (int ni = 0; ni < 8; ++ni) {
      fx4 v = acc[mi][ni];
      int gidx = (wc*32 + ni*4 + lg) ^ sx;
      uint2 pk;
      pk.x = cvtpk(v[0], v[1]);
      pk.y = cvtpk(v[2], v[3]);
      *(uint2*)&smem[m_l*256 + gidx*4] = pk;
    }
  }
  __syncthreads();

  // per-row LN: wave wv handles rows wv*16 .. wv*16+15; lane covers cols lane*4..+3
  const int c0 = lane * 4;
  float4 gv = *(const float4*)&g[c0];
  float4 bv = *(const float4*)&b[c0];
  float4 biasv = {0.f, 0.f, 0.f, 0.f};
  if constexpr (BIAS) biasv = *(const float4*)&bias[c0];
#pragma unroll 4
  for (int rr = 0; rr < 16; ++rr) {
    int r = wv*16 + rr;
    bh4 yv = *(const bh4*)&smem[r*256 + ((lane ^ ((r & 7) << 1)) << 2)];
    size_t gbase = (size_t)(m0 + r) * 256 + c0;
    float s0, s1, s2, s3;
    if constexpr (RF32) {
      float4 xv = *(const float4*)&((const float*)resid)[gbase];
      s0 = b2f((u16)yv[0]) + biasv.x + xv.x;
      s1 = b2f((u16)yv[1]) + biasv.y + xv.y;
      s2 = b2f((u16)yv[2]) + biasv.z + xv.z;
      s3 = b2f((u16)yv[3]) + biasv.w + xv.w;
    } else {
      bh4 xv = *(const bh4*)&((const u16*)resid)[gbase];
      s0 = b2f((u16)yv[0]) + biasv.x + b2f((u16)xv[0]);
      s1 = b2f((u16)yv[1]) + biasv.y + b2f((u16)xv[1]);
      s2 = b2f((u16)yv[2]) + biasv.z + b2f((u16)xv[2]);
      s3 = b2f((u16)yv[3]) + biasv.w + b2f((u16)xv[3]);
    }
    float sum = s0 + s1 + s2 + s3;
    float sq  = s0*s0 + s1*s1 + s2*s2 + s3*s3;
#pragma unroll
    for (int msk = 1; msk <= 32; msk <<= 1) {
      sum += __shfl_xor(sum, msk);
      sq  += __shfl_xor(sq, msk);
    }
    float mean = sum * 0.00390625f;
    float var  = sq  * 0.00390625f - mean*mean;
    float rs = rsqrtf(var + 1e-6f);
    float o0 = (s0 - mean)*rs*gv.x + bv.x;
    float o1 = (s1 - mean)*rs*gv.y + bv.y;
    float o2 = (s2 - mean)*rs*gv.z + bv.z;
    float o3 = (s3 - mean)*rs*gv.w + bv.w;
    if constexpr (OF32) {
      float4 o = {o0, o1, o2, o3};
      *(float4*)&((float*)out)[gbase] = o;
    } else {
      bh4 o;
      o[0] = (short)f2b(o0); o[1] = (short)f2b(o1);
      o[2] = (short)f2b(o2); o[3] = (short)f2b(o3);
      *(bh4*)&((u16*)out)[gbase] = o;
    }
  }
}

// ---------- attention: one block per (qblock, head, batch); no LDS ----------
// R9: + T5 s_setprio(1) around MFMA clusters (m191: +4-7% on attn;
// independent blocks at different phases give the scheduler role diversity).
__global__ __launch_bounds__(256) void attn_k(
    const u16* __restrict__ qw, const u16* __restrict__ kw,
    const u16* __restrict__ vtw, u16* __restrict__ ao) {
  const int qb = blockIdx.x, hh = blockIdx.y, b = blockIdx.z;
  const int tid = threadIdx.x, lane = tid & 63, wv = tid >> 6;
  const int lg = lane >> 4, ll = lane & 15;
  const int kstart = qb ? (qb - 1) * 256 : 0;
  const size_t bh_ = (size_t)(b*8 + hh);
  const u16* kg = kw  + (bh_*1024 + kstart)*32;
  const u16* vg = vtw + bh_*32*1024 + kstart;
  const u16* qg = qw  + (bh_*1024 + qb*256)*32;

  bh8 qf[4];
#pragma unroll
  for (int qi = 0; qi < 4; ++qi)
    qf[qi] = *(const bh8*)&qg[(size_t)(wv*64 + qi*16 + ll)*32 + lg*8];

  fx4 oacc[4][2] = {};
  float lsum[4] = {0.f, 0.f, 0.f, 0.f};
  const fx4 zero = {0.f, 0.f, 0.f, 0.f};

  const int ch0 = wv*2;
  const int lo_w = qb ? ch0 + 2 : 0;
  const int hi_w = qb ? ch0 + 9 : ch0 + 1;

  for (int ohm = lo_w; ohm <= hi_w; ++ohm) {
    const int kb = ohm * 32;
    bh8 kf0 = *(const bh8*)&kg[(size_t)(kb + ll)*32 + lg*8];
    bh8 kf1 = *(const bh8*)&kg[(size_t)(kb + 16 + ll)*32 + lg*8];
    s4 vb[2][2];
#pragma unroll
    for (int cs = 0; cs < 2; ++cs)
#pragma unroll
      for (int dsub = 0; dsub < 2; ++dsub)
        vb[cs][dsub] = *(const s4*)&vg[(size_t)(dsub*16 + ll)*1024 + kb + cs*16 + lg*4];

#pragma unroll
    for (int qi = 0; qi < 4; ++qi) {
      const int ch = ch0 + (qi >> 1);
      const int dlo = qb ? ch + 2 : 0;
      const int dhi = qb ? ch + 8 : ch;
      if (ohm < dlo || ohm > dhi) continue;                 // wave-uniform
      const bool diag = (ohm == dhi);

      __builtin_amdgcn_s_setprio(1);
      fx4 s0 = __builtin_amdgcn_mfma_f32_16x16x32_bf16(kf0, qf[qi], zero, 0, 0, 0);
      fx4 s1 = __builtin_amdgcn_mfma_f32_16x16x32_bf16(kf1, qf[qi], zero, 0, 0, 0);
      __builtin_amdgcn_s_setprio(0);

      const int cw = ll + ((qi & 1) << 4);
      float p[2][4];
      if (!qb && !diag) {
#pragma unroll
        for (int i = 0; i < 4; ++i) { p[0][i] = ex2(s0[i]); p[1][i] = ex2(s1[i]); }
      } else {
        const int off = (qb && !diag) ? 6 : 0;
        const unsigned thr = diag ? (qb ? 7u : 32u) : 13u;
#pragma unroll
        for (int cs = 0; cs < 2; ++cs) {
          const int tb = cw + off - cs*16 - lg*4;
          fx4 sv = cs ? s1 : s0;
#pragma unroll
          for (int i = 0; i < 4; ++i) {
            bool ok = (unsigned)(tb - i) < thr;
            p[cs][i] = ok ? ex2(sv[i]) : 0.f;
          }
        }
      }
      lsum[qi] += (p[0][0]+p[0][1]+p[0][2]+p[0][3]) + (p[1][0]+p[1][1]+p[1][2]+p[1][3]);

      __builtin_amdgcn_s_setprio(1);
#pragma unroll
      for (int cs = 0; cs < 2; ++cs) {
        union { unsigned u[2]; s4 s; } cv;
        cv.u[0] = cvtpk(p[cs][0], p[cs][1]);
        cv.u[1] = cvtpk(p[cs][2], p[cs][3]);
#pragma unroll
        for (int dsub = 0; dsub < 2; ++dsub)
          oacc[qi][dsub] = pv_mfma(cv.s, vb[cs][dsub], oacc[qi][dsub]);
      }
      __builtin_amdgcn_s_setprio(0);
    }
  }

  float rinv[4];
#pragma unroll
  for (int qi = 0; qi < 4; ++qi) {
    float v = lsum[qi];
    v += __shfl_xor(v, 16);
    v += __shfl_xor(v, 32);
    rinv[qi] = 1.0f / v;
  }

  u16* aop = ao + ((size_t)(b*1024 + qb*256))*256 + hh*32;
#pragma unroll
  for (int qi = 0; qi < 4; ++qi) {
    float rq[4];
#pragma unroll
    for (int i = 0; i < 4; ++i) rq[i] = __shfl(rinv[qi], lg*4 + i);
#pragma unroll
    for (int dsub = 0; dsub < 2; ++dsub)
#pragma unroll
      for (int i = 0; i < 4; ++i) {
        int q = wv*64 + qi*16 + lg*4 + i;
        aop[(size_t)q*256 + dsub*16 + ll] = f2b(oacc[qi][dsub][i] * rq[i]);
      }
  }
}

extern "C" void kernel_launch(void* const* d_in, const int* in_sizes, int n_in,
                              void* d_out, int out_size, void* d_ws, size_t ws_size,
                              hipStream_t stream) {
  const float* X    = (const float*)d_in[0];
  const float* Wq   = (const float*)d_in[1];
  const float* Wk   = (const float*)d_in[2];
  const float* Wv   = (const float*)d_in[3];
  const float* Wo   = (const float*)d_in[4];
  const float* ln1g = (const float*)d_in[5];
  const float* ln1b = (const float*)d_in[6];
  const float* W1   = (const float*)d_in[7];
  const float* b1   = (const float*)d_in[8];
  const float* W2   = (const float*)d_in[9];
  const float* b2   = (const float*)d_in[10];
  const float* ln2g = (const float*)d_in[11];
  const float* ln2b = (const float*)d_in[12];
  float* out = (float*)d_out;

  char* ws = (char*)d_ws;
  const size_t A = 32768ull * 256 * 2;
  u16* qws = (u16*)(ws + A);
  u16* kws = (u16*)(ws + 2*A);
  u16* vtw = (u16*)(ws + 3*A);
  u16* ao  = (u16*)(ws);          // attn out [b][l][h*32] = [32768][256]
  u16* x1b = kws;                 // LN1 out bf16
  u16* hw  = (u16*)(ws);          // relu hidden [32768][512]
  u16* WqkvT = (u16*)(ws + 4*A);
  u16* WoT = WqkvT + 196608;
  u16* W1T = WoT + 65536;
  u16* W2T = W1T + 131072;

  conv_w_k<<<2048, 256, 0, stream>>>(Wq, Wk, Wv, Wo, W1, W2, WqkvT, WoT, W1T, W2T);
  gemm_k<256, 768, 0, 1><<<dim3(6, 256), 256, 0, stream>>>(X, WqkvT, qws, kws, vtw, nullptr);
  attn_k<<<dim3(4, 8, 32), 256, 0, stream>>>(qws, kws, vtw, ao);
  gemm_ln_k<256, 1, 0, 0><<<dim3(1, 512), 256, 0, stream>>>(ao, WoT, X, nullptr, ln1g, ln1b, x1b);
  gemm_k<256, 512, 2, 0><<<dim3(4, 256), 256, 0, stream>>>(x1b, W1T, hw, nullptr, nullptr, b1);
  gemm_ln_k<512, 0, 1, 1><<<dim3(1, 512), 256, 0, stream>>>(hw, W2T, x1b, b2, ln2g, ln2b, out);
}

// Round 11
// 120.163 us; speedup vs baseline: 1.2845x; 1.0068x over previous
//
#include <hip/hip_runtime.h>

typedef unsigned short u16;
typedef __attribute__((ext_vector_type(8))) short bh8;
typedef __attribute__((ext_vector_type(4))) short s4;
typedef __attribute__((ext_vector_type(4))) short bh4;
typedef __attribute__((ext_vector_type(4))) float fx4;

__device__ __forceinline__ u16 f2b(float f) {
  union { float f; unsigned u; } v; v.f = f;
  unsigned r = v.u + 0x7fffu + ((v.u >> 16) & 1u);
  return (u16)(r >> 16);
}
__device__ __forceinline__ float b2f(u16 h) {
  union { unsigned u; float f; } v; v.u = ((unsigned)h) << 16; return v.f;
}

// fast 2^x
__device__ __forceinline__ float ex2(float x) {
#if __has_builtin(__builtin_amdgcn_exp2f)
  return __builtin_amdgcn_exp2f(x);
#else
  return __expf(x * 0.6931471805599453f);
#endif
}

// packed f32x2 -> bf16x2 (RNE, matches f2b)
__device__ __forceinline__ unsigned cvtpk(float lo, float hi) {
  unsigned r;
  asm("v_cvt_pk_bf16_f32 %0, %1, %2" : "=v"(r) : "v"(lo), "v"(hi));
  return r;
}

// 16x16x16 bf16 MFMA (K=16)
#if __has_builtin(__builtin_amdgcn_mfma_f32_16x16x16bf16_1k)
__device__ __forceinline__ fx4 pv_mfma(s4 a, s4 b, fx4 c) {
  return __builtin_amdgcn_mfma_f32_16x16x16bf16_1k(a, b, c, 0, 0, 0);
}
#else
__device__ __forceinline__ fx4 pv_mfma(s4 a, s4 b, fx4 c) {
  asm("v_mfma_f32_16x16x16_bf16 %0, %1, %2, %0" : "+v"(c) : "v"(a), "v"(b));
  return c;
}
#endif

// raw barrier with scheduling fences on BOTH sides (rule #18): prevents hipcc
// from hoisting ds_reads above the barrier or sinking them below it.
#define SBAR() do { \
  __builtin_amdgcn_sched_barrier(0); \
  __builtin_amdgcn_s_barrier(); \
  __builtin_amdgcn_sched_barrier(0); \
} while (0)

// ---------- prep: weights -> bf16, transposed to [N][K]; Wq scaled by dh^-0.5 * log2(e) ----------
__global__ __launch_bounds__(256) void conv_w_k(const float* __restrict__ Wq, const float* __restrict__ Wk,
                         const float* __restrict__ Wv, const float* __restrict__ Wo,
                         const float* __restrict__ W1, const float* __restrict__ W2,
                         u16* __restrict__ WqkvT, u16* __restrict__ WoT,
                         u16* __restrict__ W1T, u16* __restrict__ W2T) {
  int i = blockIdx.x * 256 + threadIdx.x;
  if (i < 196608) {                       // WqkvT [768][256]
    int n = i >> 8, k = i & 255; float v;
    if (n < 256) v = Wq[k*256+n] * 0.25503487359f;   // 1/sqrt(32) * log2(e)
    else if (n < 512) v = Wk[k*256+(n-256)];
    else v = Wv[k*256+(n-512)];
    WqkvT[i] = f2b(v);
  } else if (i < 262144) {                // WoT [256][256]
    int j = i - 196608; int n = j >> 8, k = j & 255;
    WoT[j] = f2b(Wo[k*256+n]);
  } else if (i < 393216) {                // W1T [512][256]
    int j = i - 262144; int n = j >> 8, k = j & 255;
    W1T[j] = f2b(W1[k*512+n]);
  } else {                                // W2T [256][512]
    int j = i - 393216; int n = j >> 9, k = j & 511;
    W2T[j] = f2b(W2[k*256+n]);
  }
}

// ---------- GEMM: C[M][N] = A[M][K] * BT[N][K]^T, bf16 in, fp32 acc ----------
// EPI 0: scatter q/k/v  2: +bias, relu
// Measured-best assembly:
//  * AF32 (QKV): counted-vmcnt 2-barrier loop w/ SBAR fences (R8/R9: 41.4us).
//    vmcnt(6) = prev-tile loads landed; this tile's 6 stay in flight.
//  * bf16 (W1): plain __syncthreads 2-phase loop (R3: best total).
// AF32=1: A is f32 staged RAW via global_load_lds; f32->bf16 at LDS-read
// time via cvt_pk; A source XOR-pre-swizzled (rule #21), conflict-free read.
template<int K, int N, int EPI, int AF32>
__global__ __launch_bounds__(256) void gemm_k(
    const void* __restrict__ Av, const u16* __restrict__ BT,
    u16* __restrict__ C0, u16* __restrict__ C1, u16* __restrict__ C2,
    const float* __restrict__ bias) {
  constexpr int BK = 32;
  constexpr int ABUF = AF32 ? 8192 : 4096;   // per-buf A stride (u16)
  constexpr int BOFF = AF32 ? 16384 : 8192;  // B region base (u16)
  __shared__ u16 smem[AF32 ? 24576 : 16384];
  const int nx = gridDim.x;
  const int lid = blockIdx.y * nx + blockIdx.x;
  const int xcd = lid & 7;
  const int jj2 = lid >> 3;
  const int m0 = (xcd * (gridDim.y >> 3) + jj2 / nx) * 128;
  const int n0 = (jj2 % nx) * 128;
  const int tid = threadIdx.x, lane = tid & 63, wv = tid >> 6;
  const int wr = wv >> 1, wc = wv & 1, lg = lane >> 4, ll = lane & 15;
  const u16* A16 = (const u16*)Av;
  const float* A32 = (const float*)Av;

  fx4 acc[4][4] = {};

  auto stageB = [&](int buf, int ks) {
#pragma unroll
    for (int i = 0; i < 2; ++i) {
      int c = i*256 + tid;
      int row = c >> 2, ko = (c & 3) * 8;
      const u16* gpB = BT + (size_t)(n0+row)*K + ks + ko;
      int lbase = BOFF + buf*4096 + (i*256 + wv*64) * 8;
      __builtin_amdgcn_global_load_lds((const __attribute__((address_space(1))) void*)gpB,
          (__attribute__((address_space(3))) void*)&smem[lbase], 16, 0, 0);
    }
  };
  auto stageA16 = [&](int buf, int ks) {
#pragma unroll
    for (int i = 0; i < 2; ++i) {
      int c = i*256 + tid;
      int row = c >> 2, ko = (c & 3) * 8;
      const u16* gpA = A16 + (size_t)(m0+row)*K + ks + ko;
      int lbase = buf*ABUF + (i*256 + wv*64) * 8;
      __builtin_amdgcn_global_load_lds((const __attribute__((address_space(1))) void*)gpA,
          (__attribute__((address_space(3))) void*)&smem[lbase], 16, 0, 0);
    }
  };
  // A f32 tile: 128 rows x 32 f32 (128B/row) = 16KB = 1024 16B chunks, 4/thread.
  // LDS linear; global source pre-swizzled: logical byte = physical ^ ((row&7)<<4).
  auto stageA32 = [&](int buf, int ks) {
#pragma unroll
    for (int i = 0; i < 4; ++i) {
      int c = i*256 + tid;
      int r = c >> 3;
      int po = (c & 7) * 16;                 // physical byte offset within row
      int lo = po ^ ((r & 7) << 4);          // logical (source) byte offset
      const float* gpA = A32 + (size_t)(m0 + r)*K + ks + (lo >> 2);
      int lbase = buf*ABUF + (i*256 + wv*64) * 8;     // u16 idx; chunk = 16B
      __builtin_amdgcn_global_load_lds((const __attribute__((address_space(1))) void*)gpA,
          (__attribute__((address_space(3))) void*)&smem[lbase], 16, 0, 0);
    }
  };

  constexpr int NT = K / BK;
  if constexpr (AF32) stageA32(0, 0); else stageA16(0, 0);
  stageB(0, 0);
  if constexpr (!AF32) __syncthreads();
  int cur = 0;
  for (int t = 0; t < NT; ++t) {
    if constexpr (AF32) {
      if (t + 1 < NT) {
        stageA32(cur ^ 1, (t+1)*BK);
        stageB(cur ^ 1, (t+1)*BK);
        asm volatile("s_waitcnt vmcnt(6)" ::: "memory");   // prev-tile loads landed
      } else {
        asm volatile("s_waitcnt vmcnt(0)" ::: "memory");
      }
      SBAR();                               // ALL waves' buf[cur] is in LDS
    } else {
      if (t + 1 < NT) {
        stageA16(cur ^ 1, (t+1)*BK);
        stageB(cur ^ 1, (t+1)*BK);
      }
    }
    bh8 af[4], bfr[4];
    if constexpr (AF32) {
#pragma unroll
      for (int mi = 0; mi < 4; ++mi) {
        int r = wr*64 + mi*16 + ll;
        int sw = (r & 7) << 4;
        int b0 = r*128 + ((lg*32) ^ sw);
        int b1 = r*128 + ((lg*32 + 16) ^ sw);
        float4 a0 = *(const float4*)&smem[cur*ABUF + (b0 >> 1)];
        float4 a1 = *(const float4*)&smem[cur*ABUF + (b1 >> 1)];
        union { unsigned u[4]; bh8 v; } cvt;
        cvt.u[0] = cvtpk(a0.x, a0.y); cvt.u[1] = cvtpk(a0.z, a0.w);
        cvt.u[2] = cvtpk(a1.x, a1.y); cvt.u[3] = cvtpk(a1.z, a1.w);
        af[mi] = cvt.v;
      }
    } else {
#pragma unroll
      for (int mi = 0; mi < 4; ++mi)
        af[mi] = *(const bh8*)&smem[cur*ABUF + (wr*64 + mi*16 + ll)*BK + lg*8];
    }
#pragma unroll
    for (int ni = 0; ni < 4; ++ni)
      bfr[ni] = *(const bh8*)&smem[BOFF + cur*4096 + (wc*64 + ni*16 + ll)*BK + lg*8];
#pragma unroll
    for (int mi = 0; mi < 4; ++mi)
#pragma unroll
      for (int ni = 0; ni < 4; ++ni)
        acc[mi][ni] = __builtin_amdgcn_mfma_f32_16x16x32_bf16(af[mi], bfr[ni], acc[mi][ni], 0, 0, 0);
    if constexpr (AF32) SBAR(); else __syncthreads();   // WAR on buf[cur]
    cur ^= 1;
  }
  if constexpr (AF32) __syncthreads();      // quiesce before C-tile aliases staging LDS

  // ---- epilogue: acc -> LDS (swizzled) -> coalesced 16B stores ----
  auto swz = [](int r) { return ((r & 14) << 2) ^ ((r & 3) << 5); };
  const bool vt = (EPI == 0) && (n0 >= 512);     // vT output blocks

  if (!vt) {
    float bv[4];
    if constexpr (EPI >= 2) {
#pragma unroll
      for (int ni = 0; ni < 4; ++ni) bv[ni] = bias[n0 + wc*64 + ni*16 + ll];
    }
#pragma unroll
    for (int mi = 0; mi < 4; ++mi)
#pragma unroll
      for (int ni = 0; ni < 4; ++ni) {
        fx4 v = acc[mi][ni];
        int n = wc*64 + ni*16 + ll;
#pragma unroll
        for (int ii = 0; ii < 2; ++ii) {
          float x0 = v[2*ii], x1 = v[2*ii+1];
          if constexpr (EPI == 2) { x0 = fmaxf(x0 + bv[ni], 0.f); x1 = fmaxf(x1 + bv[ni], 0.f); }
          unsigned pk = cvtpk(x0, x1);
          int mA = wr*64 + mi*16 + lg*4 + 2*ii;
          int mB = mA + 1;
          smem[mA*128 + (n ^ swz(mA))] = (u16)pk;
          smem[mB*128 + (n ^ swz(mB))] = (u16)(pk >> 16);
        }
      }
  } else {
    // transposed staging: LDS[n][m ^ swz(n)]
#pragma unroll
    for (int mi = 0; mi < 4; ++mi)
#pragma unroll
      for (int ni = 0; ni < 4; ++ni) {
        fx4 v = acc[mi][ni];
        int n = wc*64 + ni*16 + ll;
        int mb = wr*64 + mi*16 + lg*4;
        uint2 pk;
        pk.x = cvtpk(v[0], v[1]);
        pk.y = cvtpk(v[2], v[3]);
        *(uint2*)&smem[n*128 + (mb ^ swz(n))] = pk;
      }
  }
  __syncthreads();

#pragma unroll
  for (int j = 0; j < 8; ++j) {
    int cid = tid + 256*j;
    int row = cid >> 4, c8 = (cid & 15) << 3;
    bh8 val = *(const bh8*)&smem[row*128 + (c8 ^ swz(row))];
    if constexpr (EPI == 0) {
      if (!vt) {                                   // q/k: [b][h][l][32]
        int m = m0 + row; int b = m >> 10, l = m & 1023;
        int n = n0 + c8; int hh = (n >> 5) & 7, d = n & 31;
        size_t bh_ = (size_t)(b*8 + hh);
        u16* dst = (n0 < 256) ? C0 : C1;
        *(bh8*)&dst[(bh_*1024 + l)*32 + d] = val;
      } else {                                     // vT: [b][h][32][1024]
        int n = n0 + row; int hh = (n >> 5) & 7, d = n & 31;
        int m = m0 + c8; int b = m >> 10, l = m & 1023;
        size_t bh_ = (size_t)(b*8 + hh);
        *(bh8*)&C2[(bh_*32 + d)*1024 + l] = val;
      }
    } else {
      *(bh8*)&C0[(size_t)(m0+row)*N + n0 + c8] = val;
    }
  }
}

// ---------- fused GEMM + residual + LayerNorm ----------
// Verbatim R3 passing version (best total): 64x256 tile, 4 waves,
// 2-buf __syncthreads K-loop.
template<int K, int RF32, int OF32, int BIAS>
__global__ __launch_bounds__(256) void gemm_ln_k(
    const u16* __restrict__ A, const u16* __restrict__ BT,
    const void* __restrict__ resid, const float* __restrict__ bias,
    const float* __restrict__ g, const float* __restrict__ b,
    void* __restrict__ out) {
  constexpr int BK = 32;
  __shared__ u16 smem[20480];   // A dbuf [2][2048) @0, B dbuf [2][8192) @4096; C tile [64][256] @0
  const int lid = blockIdx.y;
  const int xcd = lid & 7;
  const int jj2 = lid >> 3;
  const int m0 = (xcd * (gridDim.y >> 3) + jj2) * 64;
  const int tid = threadIdx.x, lane = tid & 63, wv = tid >> 6;
  const int wr = wv >> 1, wc = wv & 1, lg = lane >> 4, ll = lane & 15;

  fx4 acc[2][8] = {};

  auto stage = [&](int buf, int ks) {
    {
      int c = tid;
      int row = c >> 2, ko = (c & 3) * 8;
      const u16* gpA = A + (size_t)(m0+row)*K + ks + ko;
      int lbase = wv*512;
      __builtin_amdgcn_global_load_lds((const __attribute__((address_space(1))) void*)gpA,
          (__attribute__((address_space(3))) void*)&smem[buf*2048 + lbase], 16, 0, 0);
    }
#pragma unroll
    for (int i = 0; i < 4; ++i) {
      int c = i*256 + tid;
      int row = c >> 2, ko = (c & 3) * 8;
      const u16* gpB = BT + (size_t)row*K + ks + ko;
      int lbase = (i*256 + wv*64) * 8;
      __builtin_amdgcn_global_load_lds((const __attribute__((address_space(1))) void*)gpB,
          (__attribute__((address_space(3))) void*)&smem[4096 + buf*8192 + lbase], 16, 0, 0);
    }
  };

  constexpr int NT = K / BK;
  stage(0, 0);
  __syncthreads();
  int cur = 0;
  for (int t = 0; t < NT; ++t) {
    if (t + 1 < NT) stage(cur ^ 1, (t+1)*BK);
    bh8 af[2], bfr[8];
#pragma unroll
    for (int mi = 0; mi < 2; ++mi)
      af[mi] = *(const bh8*)&smem[cur*2048 + (wr*32 + mi*16 + ll)*BK + lg*8];
#pragma unroll
    for (int ni = 0; ni < 8; ++ni)
      bfr[ni] = *(const bh8*)&smem[4096 + cur*8192 + (wc*128 + ni*16 + ll)*BK + lg*8];
#pragma unroll
    for (int mi = 0; mi < 2; ++mi)
#pragma unroll
      for (int ni = 0; ni < 8; ++ni)
        acc[mi][ni] = __builtin_amdgcn_mfma_f32_16x16x32_bf16(bfr[ni], af[mi], acc[mi][ni], 0, 0, 0);
    __syncthreads();
    cur ^= 1;
  }

  // stage C tile: row m_l = wr*32+mi*16+ll, cols n_l..n_l+3 = wc*128+ni*16+lg*4
#pragma unroll
  for (int mi = 0; mi < 2; ++mi) {
    int m_l = wr*32 + mi*16 + ll;
    int sx = (m_l & 7) << 1;
#pragma unroll
    for (int ni = 0; ni < 8; ++ni) {
      fx4 v = acc[mi][ni];
      int gidx = (wc*32 + ni*4 + lg) ^ sx;
      uint2 pk;
      pk.x = cvtpk(v[0], v[1]);
      pk.y = cvtpk(v[2], v[3]);
      *(uint2*)&smem[m_l*256 + gidx*4] = pk;
    }
  }
  __syncthreads();

  // per-row LN: wave wv handles rows wv*16 .. wv*16+15; lane covers cols lane*4..+3
  const int c0 = lane * 4;
  float4 gv = *(const float4*)&g[c0];
  float4 bv = *(const float4*)&b[c0];
  float4 biasv = {0.f, 0.f, 0.f, 0.f};
  if constexpr (BIAS) biasv = *(const float4*)&bias[c0];
#pragma unroll 4
  for (int rr = 0; rr < 16; ++rr) {
    int r = wv*16 + rr;
    bh4 yv = *(const bh4*)&smem[r*256 + ((lane ^ ((r & 7) << 1)) << 2)];
    size_t gbase = (size_t)(m0 + r) * 256 + c0;
    float s0, s1, s2, s3;
    if constexpr (RF32) {
      float4 xv = *(const float4*)&((const float*)resid)[gbase];
      s0 = b2f((u16)yv[0]) + biasv.x + xv.x;
      s1 = b2f((u16)yv[1]) + biasv.y + xv.y;
      s2 = b2f((u16)yv[2]) + biasv.z + xv.z;
      s3 = b2f((u16)yv[3]) + biasv.w + xv.w;
    } else {
      bh4 xv = *(const bh4*)&((const u16*)resid)[gbase];
      s0 = b2f((u16)yv[0]) + biasv.x + b2f((u16)xv[0]);
      s1 = b2f((u16)yv[1]) + biasv.y + b2f((u16)xv[1]);
      s2 = b2f((u16)yv[2]) + biasv.z + b2f((u16)xv[2]);
      s3 = b2f((u16)yv[3]) + biasv.w + b2f((u16)xv[3]);
    }
    float sum = s0 + s1 + s2 + s3;
    float sq  = s0*s0 + s1*s1 + s2*s2 + s3*s3;
#pragma unroll
    for (int msk = 1; msk <= 32; msk <<= 1) {
      sum += __shfl_xor(sum, msk);
      sq  += __shfl_xor(sq, msk);
    }
    float mean = sum * 0.00390625f;
    float var  = sq  * 0.00390625f - mean*mean;
    float rs = rsqrtf(var + 1e-6f);
    float o0 = (s0 - mean)*rs*gv.x + bv.x;
    float o1 = (s1 - mean)*rs*gv.y + bv.y;
    float o2 = (s2 - mean)*rs*gv.z + bv.z;
    float o3 = (s3 - mean)*rs*gv.w + bv.w;
    if constexpr (OF32) {
      float4 o = {o0, o1, o2, o3};
      *(float4*)&((float*)out)[gbase] = o;
    } else {
      bh4 o;
      o[0] = (short)f2b(o0); o[1] = (short)f2b(o1);
      o[2] = (short)f2b(o2); o[3] = (short)f2b(o3);
      *(bh4*)&((u16*)out)[gbase] = o;
    }
  }
}

// ---------- attention: one block per (qblock, head, batch); no LDS ----------
// Verbatim R3 known-good kernel (setprio removed: R9 showed it costs ~2us here
// — co-resident blocks are phase-aligned, so prio just starves neighbor loads).
__global__ __launch_bounds__(256) void attn_k(
    const u16* __restrict__ qw, const u16* __restrict__ kw,
    const u16* __restrict__ vtw, u16* __restrict__ ao) {
  const int qb = blockIdx.x, hh = blockIdx.y, b = blockIdx.z;
  const int tid = threadIdx.x, lane = tid & 63, wv = tid >> 6;
  const int lg = lane >> 4, ll = lane & 15;
  const int kstart = qb ? (qb - 1) * 256 : 0;
  const size_t bh_ = (size_t)(b*8 + hh);
  const u16* kg = kw  + (bh_*1024 + kstart)*32;
  const u16* vg = vtw + bh_*32*1024 + kstart;
  const u16* qg = qw  + (bh_*1024 + qb*256)*32;

  bh8 qf[4];
#pragma unroll
  for (int qi = 0; qi < 4; ++qi)
    qf[qi] = *(const bh8*)&qg[(size_t)(wv*64 + qi*16 + ll)*32 + lg*8];

  fx4 oacc[4][2] = {};
  float lsum[4] = {0.f, 0.f, 0.f, 0.f};
  const fx4 zero = {0.f, 0.f, 0.f, 0.f};

  const int ch0 = wv*2;
  const int lo_w = qb ? ch0 + 2 : 0;
  const int hi_w = qb ? ch0 + 9 : ch0 + 1;

  for (int ohm = lo_w; ohm <= hi_w; ++ohm) {
    const int kb = ohm * 32;
    bh8 kf0 = *(const bh8*)&kg[(size_t)(kb + ll)*32 + lg*8];
    bh8 kf1 = *(const bh8*)&kg[(size_t)(kb + 16 + ll)*32 + lg*8];
    s4 vb[2][2];
#pragma unroll
    for (int cs = 0; cs < 2; ++cs)
#pragma unroll
      for (int dsub = 0; dsub < 2; ++dsub)
        vb[cs][dsub] = *(const s4*)&vg[(size_t)(dsub*16 + ll)*1024 + kb + cs*16 + lg*4];

#pragma unroll
    for (int qi = 0; qi < 4; ++qi) {
      const int ch = ch0 + (qi >> 1);
      const int dlo = qb ? ch + 2 : 0;
      const int dhi = qb ? ch + 8 : ch;
      if (ohm < dlo || ohm > dhi) continue;                 // wave-uniform
      const bool diag = (ohm == dhi);

      fx4 s0 = __builtin_amdgcn_mfma_f32_16x16x32_bf16(kf0, qf[qi], zero, 0, 0, 0);
      fx4 s1 = __builtin_amdgcn_mfma_f32_16x16x32_bf16(kf1, qf[qi], zero, 0, 0, 0);

      const int cw = ll + ((qi & 1) << 4);
      float p[2][4];
      if (!qb && !diag) {
#pragma unroll
        for (int i = 0; i < 4; ++i) { p[0][i] = ex2(s0[i]); p[1][i] = ex2(s1[i]); }
      } else {
        const int off = (qb && !diag) ? 6 : 0;
        const unsigned thr = diag ? (qb ? 7u : 32u) : 13u;
#pragma unroll
        for (int cs = 0; cs < 2; ++cs) {
          const int tb = cw + off - cs*16 - lg*4;
          fx4 sv = cs ? s1 : s0;
#pragma unroll
          for (int i = 0; i < 4; ++i) {
            bool ok = (unsigned)(tb - i) < thr;
            p[cs][i] = ok ? ex2(sv[i]) : 0.f;
          }
        }
      }
      lsum[qi] += (p[0][0]+p[0][1]+p[0][2]+p[0][3]) + (p[1][0]+p[1][1]+p[1][2]+p[1][3]);

#pragma unroll
      for (int cs = 0; cs < 2; ++cs) {
        union { unsigned u[2]; s4 s; } cv;
        cv.u[0] = cvtpk(p[cs][0], p[cs][1]);
        cv.u[1] = cvtpk(p[cs][2], p[cs][3]);
#pragma unroll
        for (int dsub = 0; dsub < 2; ++dsub)
          oacc[qi][dsub] = pv_mfma(cv.s, vb[cs][dsub], oacc[qi][dsub]);
      }
    }
  }

  float rinv[4];
#pragma unroll
  for (int qi = 0; qi < 4; ++qi) {
    float v = lsum[qi];
    v += __shfl_xor(v, 16);
    v += __shfl_xor(v, 32);
    rinv[qi] = 1.0f / v;
  }

  u16* aop = ao + ((size_t)(b*1024 + qb*256))*256 + hh*32;
#pragma unroll
  for (int qi = 0; qi < 4; ++qi) {
    float rq[4];
#pragma unroll
    for (int i = 0; i < 4; ++i) rq[i] = __shfl(rinv[qi], lg*4 + i);
#pragma unroll
    for (int dsub = 0; dsub < 2; ++dsub)
#pragma unroll
      for (int i = 0; i < 4; ++i) {
        int q = wv*64 + qi*16 + lg*4 + i;
        aop[(size_t)q*256 + dsub*16 + ll] = f2b(oacc[qi][dsub][i] * rq[i]);
      }
  }
}

extern "C" void kernel_launch(void* const* d_in, const int* in_sizes, int n_in,
                              void* d_out, int out_size, void* d_ws, size_t ws_size,
                              hipStream_t stream) {
  const float* X    = (const float*)d_in[0];
  const float* Wq   = (const float*)d_in[1];
  const float* Wk   = (const float*)d_in[2];
  const float* Wv   = (const float*)d_in[3];
  const float* Wo   = (const float*)d_in[4];
  const float* ln1g = (const float*)d_in[5];
  const float* ln1b = (const float*)d_in[6];
  const float* W1   = (const float*)d_in[7];
  const float* b1   = (const float*)d_in[8];
  const float* W2   = (const float*)d_in[9];
  const float* b2   = (const float*)d_in[10];
  const float* ln2g = (const float*)d_in[11];
  const float* ln2b = (const float*)d_in[12];
  float* out = (float*)d_out;

  char* ws = (char*)d_ws;
  const size_t A = 32768ull * 256 * 2;
  u16* qws = (u16*)(ws + A);
  u16* kws = (u16*)(ws + 2*A);
  u16* vtw = (u16*)(ws + 3*A);
  u16* ao  = (u16*)(ws);          // attn out [b][l][h*32] = [32768][256]
  u16* x1b = kws;                 // LN1 out bf16
  u16* hw  = (u16*)(ws);          // relu hidden [32768][512]
  u16* WqkvT = (u16*)(ws + 4*A);
  u16* WoT = WqkvT + 196608;
  u16* W1T = WoT + 65536;
  u16* W2T = W1T + 131072;

  conv_w_k<<<2048, 256, 0, stream>>>(Wq, Wk, Wv, Wo, W1, W2, WqkvT, WoT, W1T, W2T);
  gemm_k<256, 768, 0, 1><<<dim3(6, 256), 256, 0, stream>>>(X, WqkvT, qws, kws, vtw, nullptr);
  attn_k<<<dim3(4, 8, 32), 256, 0, stream>>>(qws, kws, vtw, ao);
  gemm_ln_k<256, 1, 0, 0><<<dim3(1, 512), 256, 0, stream>>>(ao, WoT, X, nullptr, ln1g, ln1b, x1b);
  gemm_k<256, 512, 2, 0><<<dim3(4, 256), 256, 0, stream>>>(x1b, W1T, hw, nullptr, nullptr, b1);
  gemm_ln_k<512, 0, 1, 1><<<dim3(1, 512), 256, 0, stream>>>(hw, W2T, x1b, b2, ln2g, ln2b, out);
}